// Round 8
// baseline (881.567 us; speedup 1.0000x reference)
//
#include <hip/hip_runtime.h>
#include <hip/hip_bf16.h>

// ---------------------------------------------------------------------------
// Switch Transformer encoder layer, MI355X/gfx950.
// S=2048 B=2 D=768 H=12 DH=64 F=3072 E=8 T=4096 CAP=1024.
// Interface: f32 in / f32 out. Pre-router chain uses SPLIT-BF16 MFMA
// (x = hi + lo, 3 MFMAs per product => ~2^-18 relative error) so the
// router argmax matches the f32 reference. MoE FFN is plain bf16 MFMA.
// R8: (1) attn: P-tiles alias the K LDS region (post-QK barrier) ->
//     LDS 52.2KB -> 34.8KB -> 4 blocks/CU, __launch_bounds__(256,4);
//     (2) all GEMM mainloops stage via global_load_lds width=16 (m97).
// ---------------------------------------------------------------------------

#define S_   2048
#define B_   2
#define D_   768
#define H_   12
#define DH_  64
#define F_   3072
#define E_   8
#define T_   4096
#define CAP_ 1024

#define AP_  68   // attn LDS row stride (elems): 64 + 4 pad

typedef __hip_bfloat16 bf16;
using short8  = __attribute__((ext_vector_type(8))) short;
using floatx4 = __attribute__((ext_vector_type(4))) float;

__device__ __forceinline__ float b2f(bf16 x) { return __bfloat162float(x); }
__device__ __forceinline__ bf16  f2b(float x) { return __float2bfloat16(x); }

// async global->LDS, 16B/lane; LDS dest = wave-uniform base + lane*16B
__device__ __forceinline__ void gld_lds16(const bf16* g, bf16* l) {
  __builtin_amdgcn_global_load_lds(
      (const __attribute__((address_space(1))) void*)g,
      (__attribute__((address_space(3))) void*)l, 16, 0, 0);
}

struct SrcPair { const bf16* h; const bf16* l; };  // pre-split hi/lo

// f32 -> (hi, lo) bf16 split, 4 elems/thread
__global__ __launch_bounds__(256) void split_kernel(
    const float* __restrict__ x, bf16* __restrict__ h, bf16* __restrict__ l,
    int n4) {
  int i = blockIdx.x * 256 + threadIdx.x;
  if (i >= n4) return;
  float4 v = ((const float4*)x)[i];
  float va[4] = {v.x, v.y, v.z, v.w};
  __attribute__((aligned(8))) bf16 hh[4], ll[4];
#pragma unroll
  for (int j = 0; j < 4; j++) {
    bf16 t = f2b(va[j]);
    hh[j] = t;
    ll[j] = f2b(va[j] - b2f(t));
  }
  *(uint2*)(h + (size_t)i * 4) = *(const uint2*)hh;
  *(uint2*)(l + (size_t)i * 4) = *(const uint2*)ll;
}

// ---------------------------------------------------------------------------
// SPLIT GEMM mainloop: C128x128 += A[128,K]*W[128,K]^T in ~f32 precision.
// m97 staging: global_load_lds width=16, 2 barriers, [128][32] LDS tiles.
// Wave w stages rows w*32..+31 (lane -> base + lane*16B = row lane>>2,
// col (lane&3)*8); owns output quadrant ((w>>1)*64,(w&1)*64).
// ---------------------------------------------------------------------------
__device__ __forceinline__ void gemm_split_loop(
    SrcPair A, SrcPair W, int K,
    bf16* AsH, bf16* AsL, bf16* WsH, bf16* WsL, floatx4 (&acc)[4][4]) {
  const int tid = threadIdx.x;
  const int w = tid >> 6, lane = tid & 63;
  const int srow = lane >> 2;
  const int scol = (lane & 3) * 8;
  const bf16* Ah = A.h + (size_t)(w * 32 + srow) * K + scol;
  const bf16* Al = A.l + (size_t)(w * 32 + srow) * K + scol;
  const bf16* Wh = W.h + (size_t)(w * 32 + srow) * K + scol;
  const bf16* Wl = W.l + (size_t)(w * 32 + srow) * K + scol;
  bf16* AsHb = AsH + w * 1024;   // wave-uniform LDS bases
  bf16* AsLb = AsL + w * 1024;
  bf16* WsHb = WsH + w * 1024;
  bf16* WsLb = WsL + w * 1024;
  const int wm = (w >> 1) * 64, wn = (w & 1) * 64;
  const int fr = lane & 15, g = lane >> 4;

  for (int kt = 0; kt < K; kt += 32) {
    gld_lds16(Ah, AsHb); gld_lds16(Ah + 16 * (size_t)K, AsHb + 512);
    gld_lds16(Al, AsLb); gld_lds16(Al + 16 * (size_t)K, AsLb + 512);
    gld_lds16(Wh, WsHb); gld_lds16(Wh + 16 * (size_t)K, WsHb + 512);
    gld_lds16(Wl, WsLb); gld_lds16(Wl + 16 * (size_t)K, WsLb + 512);
    Ah += 32; Al += 32; Wh += 32; Wl += 32;
    __syncthreads();
    short8 afh[4], afl[4], bfh[4], bfl[4];
#pragma unroll
    for (int mi = 0; mi < 4; mi++) {
      int o = (wm + mi * 16 + fr) * 32 + g * 8;
      afh[mi] = *(const short8*)&AsH[o];
      afl[mi] = *(const short8*)&AsL[o];
    }
#pragma unroll
    for (int ni = 0; ni < 4; ni++) {
      int o = (wn + ni * 16 + fr) * 32 + g * 8;
      bfh[ni] = *(const short8*)&WsH[o];
      bfl[ni] = *(const short8*)&WsL[o];
    }
#pragma unroll
    for (int mi = 0; mi < 4; mi++)
#pragma unroll
      for (int ni = 0; ni < 4; ni++) {
        floatx4 z = acc[mi][ni];
        z = __builtin_amdgcn_mfma_f32_16x16x32_bf16(afh[mi], bfh[ni], z, 0, 0, 0);
        z = __builtin_amdgcn_mfma_f32_16x16x32_bf16(afh[mi], bfl[ni], z, 0, 0, 0);
        z = __builtin_amdgcn_mfma_f32_16x16x32_bf16(afl[mi], bfh[ni], z, 0, 0, 0);
        acc[mi][ni] = z;
      }
    __syncthreads();
  }
}

// Split GEMM, split-pair output: C = A·W^T + bias -> (Chi, Clo)
__global__ __launch_bounds__(256) void gemm_split_pairout(
    SrcPair A, SrcPair W, const float* __restrict__ bias,
    bf16* __restrict__ Chi, bf16* __restrict__ Clo, int N, int K) {
  __shared__ __attribute__((aligned(16))) bf16 AsH[4096], AsL[4096];
  __shared__ __attribute__((aligned(16))) bf16 WsH[4096], WsL[4096];
  const int m0 = blockIdx.y * 128, n0 = blockIdx.x * 128;
  floatx4 acc[4][4];
#pragma unroll
  for (int i = 0; i < 4; i++)
#pragma unroll
    for (int j = 0; j < 4; j++) acc[i][j] = (floatx4){0.f, 0.f, 0.f, 0.f};
  SrcPair Aoff{A.h + (size_t)m0 * K, A.l + (size_t)m0 * K};
  SrcPair Woff{W.h + (size_t)n0 * K, W.l + (size_t)n0 * K};
  gemm_split_loop(Aoff, Woff, K, AsH, AsL, WsH, WsL, acc);

  const int tid = threadIdx.x, w = tid >> 6, lane = tid & 63;
  const int wm = (w >> 1) * 64, wn = (w & 1) * 64;
  const int fr = lane & 15, rg = (lane >> 4) * 4;
#pragma unroll
  for (int mi = 0; mi < 4; mi++) {
#pragma unroll
    for (int ni = 0; ni < 4; ni++) {
      int n = n0 + wn + ni * 16 + fr;
      float bv = bias[n];
#pragma unroll
      for (int r = 0; r < 4; r++) {
        int m = m0 + wm + mi * 16 + rg + r;
        float v = acc[mi][ni][r] + bv;
        bf16 hh = f2b(v);
        Chi[(size_t)m * N + n] = hh;
        Clo[(size_t)m * N + n] = f2b(v - b2f(hh));
      }
    }
  }
}

// Split GEMM, f32 output + f32 residual: C = A·W^T + bias + resid
__global__ __launch_bounds__(256) void gemm_split_f32out(
    SrcPair A, SrcPair W, const float* __restrict__ bias,
    const float* __restrict__ resid, float* __restrict__ C, int N, int K) {
  __shared__ __attribute__((aligned(16))) bf16 AsH[4096], AsL[4096];
  __shared__ __attribute__((aligned(16))) bf16 WsH[4096], WsL[4096];
  const int m0 = blockIdx.y * 128, n0 = blockIdx.x * 128;
  floatx4 acc[4][4];
#pragma unroll
  for (int i = 0; i < 4; i++)
#pragma unroll
    for (int j = 0; j < 4; j++) acc[i][j] = (floatx4){0.f, 0.f, 0.f, 0.f};
  SrcPair Aoff{A.h + (size_t)m0 * K, A.l + (size_t)m0 * K};
  SrcPair Woff{W.h + (size_t)n0 * K, W.l + (size_t)n0 * K};
  gemm_split_loop(Aoff, Woff, K, AsH, AsL, WsH, WsL, acc);

  const int tid = threadIdx.x, w = tid >> 6, lane = tid & 63;
  const int wm = (w >> 1) * 64, wn = (w & 1) * 64;
  const int fr = lane & 15, rg = (lane >> 4) * 4;
#pragma unroll
  for (int mi = 0; mi < 4; mi++) {
#pragma unroll
    for (int ni = 0; ni < 4; ni++) {
      int n = n0 + wn + ni * 16 + fr;
      float bv = bias[n];
#pragma unroll
      for (int r = 0; r < 4; r++) {
        int m = m0 + wm + mi * 16 + rg + r;
        C[(size_t)m * N + n] = acc[mi][ni][r] + bv + resid[(size_t)m * N + n];
      }
    }
  }
}

// ---------------------------------------------------------------------------
// Plain bf16 GEMM mainloop (MoE path), m97 global_load_lds staging.
// ---------------------------------------------------------------------------
__device__ __forceinline__ void gemm_tile_loop(
    const bf16* __restrict__ Ablk, const bf16* __restrict__ Wblk, int K,
    bf16* As, bf16* Ws, floatx4 (&acc)[4][4]) {
  const int tid = threadIdx.x;
  const int w = tid >> 6, lane = tid & 63;
  const int srow = lane >> 2;
  const int scol = (lane & 3) * 8;
  const bf16* Ag = Ablk + (size_t)(w * 32 + srow) * K + scol;
  const bf16* Wg = Wblk + (size_t)(w * 32 + srow) * K + scol;
  bf16* Asb = As + w * 1024;
  bf16* Wsb = Ws + w * 1024;
  const int wm = (w >> 1) * 64, wn = (w & 1) * 64;
  const int fr = lane & 15, g = lane >> 4;

  for (int kt = 0; kt < K; kt += 32) {
    gld_lds16(Ag, Asb); gld_lds16(Ag + 16 * (size_t)K, Asb + 512);
    gld_lds16(Wg, Wsb); gld_lds16(Wg + 16 * (size_t)K, Wsb + 512);
    Ag += 32; Wg += 32;
    __syncthreads();
    short8 af[4], bfg[4];
#pragma unroll
    for (int mi = 0; mi < 4; mi++)
      af[mi] = *(const short8*)&As[(wm + mi * 16 + fr) * 32 + g * 8];
#pragma unroll
    for (int ni = 0; ni < 4; ni++)
      bfg[ni] = *(const short8*)&Ws[(wn + ni * 16 + fr) * 32 + g * 8];
#pragma unroll
    for (int mi = 0; mi < 4; mi++)
#pragma unroll
      for (int ni = 0; ni < 4; ni++)
        acc[mi][ni] = __builtin_amdgcn_mfma_f32_16x16x32_bf16(
            af[mi], bfg[ni], acc[mi][ni], 0, 0, 0);
    __syncthreads();
  }
}

// MoE FFN layer 1: h = relu(xe @ w1t^T + b1)
__global__ __launch_bounds__(256) void moe1_kernel(
    const bf16* __restrict__ xe, const bf16* __restrict__ w1t,
    const float* __restrict__ b1, bf16* __restrict__ h,
    const int* __restrict__ counts) {
  const int e = blockIdx.y >> 3, lt = blockIdx.y & 7;
  int kept = counts[e]; if (kept > CAP_) kept = CAP_;
  if (lt * 128 >= kept) return;
  __shared__ __attribute__((aligned(16))) bf16 As[4096];
  __shared__ __attribute__((aligned(16))) bf16 Ws[4096];
  const int n0 = blockIdx.x * 128;
  floatx4 acc[4][4];
#pragma unroll
  for (int i = 0; i < 4; i++)
#pragma unroll
    for (int j = 0; j < 4; j++) acc[i][j] = (floatx4){0.f, 0.f, 0.f, 0.f};
  gemm_tile_loop(xe + (size_t)(e * CAP_ + lt * 128) * D_,
                 w1t + (size_t)e * F_ * D_ + (size_t)n0 * D_, D_, As, Ws, acc);

  const int tid = threadIdx.x, w = tid >> 6, lane = tid & 63;
  const int wm = (w >> 1) * 64, wn = (w & 1) * 64;
  const int fr = lane & 15, rg = (lane >> 4) * 4;
#pragma unroll
  for (int mi = 0; mi < 4; mi++) {
#pragma unroll
    for (int ni = 0; ni < 4; ni++) {
      int n = n0 + wn + ni * 16 + fr;
      float bv = b1[e * F_ + n];
#pragma unroll
      for (int r = 0; r < 4; r++) {
        int mrow = lt * 128 + wm + mi * 16 + rg + r;
        h[(size_t)(e * CAP_ + mrow) * F_ + n] =
            f2b(fmaxf(acc[mi][ni][r] + bv, 0.f));
      }
    }
  }
}

// MoE FFN layer 2 + gate + scatter
__global__ __launch_bounds__(256) void moe2_kernel(
    const bf16* __restrict__ h, const bf16* __restrict__ w2t,
    const float* __restrict__ bias2, const int* __restrict__ stok,
    const float* __restrict__ sgate, const int* __restrict__ counts,
    bf16* __restrict__ moe) {
  const int e = blockIdx.y >> 3, lt = blockIdx.y & 7;
  int kept = counts[e]; if (kept > CAP_) kept = CAP_;
  if (lt * 128 >= kept) return;
  __shared__ __attribute__((aligned(16))) bf16 As[4096];
  __shared__ __attribute__((aligned(16))) bf16 Ws[4096];
  const int n0 = blockIdx.x * 128;
  floatx4 acc[4][4];
#pragma unroll
  for (int i = 0; i < 4; i++)
#pragma unroll
    for (int j = 0; j < 4; j++) acc[i][j] = (floatx4){0.f, 0.f, 0.f, 0.f};
  gemm_tile_loop(h + (size_t)(e * CAP_ + lt * 128) * F_,
                 w2t + (size_t)e * D_ * F_ + (size_t)n0 * F_, F_, As, Ws, acc);

  const int tid = threadIdx.x, w = tid >> 6, lane = tid & 63;
  const int wm = (w >> 1) * 64, wn = (w & 1) * 64;
  const int fr = lane & 15, rg = (lane >> 4) * 4;
#pragma unroll
  for (int mi = 0; mi < 4; mi++) {
#pragma unroll
    for (int r = 0; r < 4; r++) {
      int mrow = lt * 128 + wm + mi * 16 + rg + r;
      int slot = e * CAP_ + mrow;
      int t = stok[slot];
      if (t < 0) continue;
      float gt = sgate[slot];
#pragma unroll
      for (int ni = 0; ni < 4; ni++) {
        int n = n0 + wn + ni * 16 + fr;
        moe[(size_t)t * D_ + n] = f2b((acc[mi][ni][r] + bias2[e * D_ + n]) * gt);
      }
    }
  }
}

// ---------------------------------------------------------------------------
// V pre-transpose: qkv V-slice (hi+lo) -> vt[bh][dh][S] (hi+lo).
// ---------------------------------------------------------------------------
__global__ __launch_bounds__(256) void vtrans2_kernel(
    const bf16* __restrict__ qh, const bf16* __restrict__ ql,
    bf16* __restrict__ vth, bf16* __restrict__ vtl) {
  __shared__ bf16 th[64][65], tl[64][65];
  const int tid = threadIdx.x;
  const int bh = blockIdx.y, b = bh / H_, hh = bh % H_;
  const int s0 = blockIdx.x * 64;
#pragma unroll
  for (int i = 0; i < 2; i++) {
    int rr = i * 32 + tid / 8, cc = (tid % 8) * 8;
    size_t off = (size_t)((s0 + rr) * B_ + b) * (3 * D_) + 2 * D_ + hh * DH_ + cc;
    short8 vh = *(const short8*)(qh + off);
    short8 vl = *(const short8*)(ql + off);
    const bf16* ph = (const bf16*)&vh;
    const bf16* pl = (const bf16*)&vl;
#pragma unroll
    for (int j = 0; j < 8; j++) { th[rr][cc + j] = ph[j]; tl[rr][cc + j] = pl[j]; }
  }
  __syncthreads();
#pragma unroll
  for (int i = 0; i < 2; i++) {
    int cc = i * 32 + tid / 8, rr = (tid % 8) * 8;
    __attribute__((aligned(16))) bf16 a[8], c[8];
#pragma unroll
    for (int j = 0; j < 8; j++) { a[j] = th[rr + j][cc]; c[j] = tl[rr + j][cc]; }
    size_t off = ((size_t)bh * DH_ + cc) * S_ + s0 + rr;
    *(short8*)(vth + off) = *(const short8*)a;
    *(short8*)(vtl + off) = *(const short8*)c;
  }
}

// ---------------------------------------------------------------------------
// Flash attention, split-bf16, register prefetch. P-tiles alias the K LDS
// region (K fully consumed by end of QK; post-QK barrier guards overwrite).
// LDS = 2*64*AP (K/P union) + 2*64*AP (V) = 34,816 B -> 4 blocks/CU.
// ---------------------------------------------------------------------------
__global__ __launch_bounds__(256, 4) void attn_kernel(
    const bf16* __restrict__ qh, const bf16* __restrict__ ql,
    const bf16* __restrict__ vth, const bf16* __restrict__ vtl,
    bf16* __restrict__ ch, bf16* __restrict__ cl) {
  __shared__ __attribute__((aligned(16))) bf16 KP[2 * 64 * AP_];  // K hi/lo, aliased by P hi/lo
  __shared__ __attribute__((aligned(16))) bf16 VsH[64 * AP_], VsL[64 * AP_];
  const int tid = threadIdx.x, w = tid >> 6, lane = tid & 63;
  const int bh = blockIdx.y, b = bh / H_, hh = bh % H_;
  const int q0 = blockIdx.x * 64;
  const int fr = lane & 15, g = lane >> 4;
  bf16* KsH = KP;
  bf16* KsL = KP + 64 * AP_;
  bf16* PwH = KP + w * (16 * AP_);              // wave-private P slices
  bf16* PwL = KP + 64 * AP_ + w * (16 * AP_);

  const int qs = q0 + w * 16 + fr;
  const size_t qoff = (size_t)(qs * B_ + b) * (3 * D_) + hh * DH_;
  const short8 qf0h = *(const short8*)(qh + qoff + g * 8);
  const short8 qf1h = *(const short8*)(qh + qoff + 32 + g * 8);
  const short8 qf0l = *(const short8*)(ql + qoff + g * 8);
  const short8 qf1l = *(const short8*)(ql + qoff + 32 + g * 8);

  float mi_[4], li_[4], alpha[4];
  floatx4 o[4];
#pragma unroll
  for (int r = 0; r < 4; r++) { mi_[r] = -1e30f; li_[r] = 0.f; }
#pragma unroll
  for (int nt = 0; nt < 4; nt++) o[nt] = (floatx4){0.f, 0.f, 0.f, 0.f};

  const int str = tid >> 2;            // staged row 0..63 (key for K, dh for V)
  const int st16 = (tid & 3) * 16;     // 16-elem chunk

  // prefetch tile 0 into registers
  size_t koff = (size_t)(str * B_ + b) * (3 * D_) + D_ + hh * DH_ + st16;
  size_t voff = ((size_t)bh * DH_ + str) * S_ + st16;
  short8 pk0h = *(const short8*)(qh + koff);
  short8 pk1h = *(const short8*)(qh + koff + 8);
  short8 pk0l = *(const short8*)(ql + koff);
  short8 pk1l = *(const short8*)(ql + koff + 8);
  short8 pv0h = *(const short8*)(vth + voff);
  short8 pv1h = *(const short8*)(vth + voff + 8);
  short8 pv0l = *(const short8*)(vtl + voff);
  short8 pv1l = *(const short8*)(vtl + voff + 8);

  for (int kb = 0; kb < S_ / 64; kb++) {
    __syncthreads();   // B1: prior PV done (P + V reads) -> restage K/V
    *(short8*)&KsH[str * AP_ + st16]     = pk0h;
    *(short8*)&KsH[str * AP_ + st16 + 8] = pk1h;
    *(short8*)&KsL[str * AP_ + st16]     = pk0l;
    *(short8*)&KsL[str * AP_ + st16 + 8] = pk1l;
    *(short8*)&VsH[str * AP_ + st16]     = pv0h;
    *(short8*)&VsH[str * AP_ + st16 + 8] = pv1h;
    *(short8*)&VsL[str * AP_ + st16]     = pv0l;
    *(short8*)&VsL[str * AP_ + st16 + 8] = pv1l;
    __syncthreads();   // B2: staged tile visible

    if (kb + 1 < S_ / 64) {   // prefetch next tile; overlaps compute below
      koff += (size_t)64 * B_ * (3 * D_);
      voff += 64;
      pk0h = *(const short8*)(qh + koff);
      pk1h = *(const short8*)(qh + koff + 8);
      pk0l = *(const short8*)(ql + koff);
      pk1l = *(const short8*)(ql + koff + 8);
      pv0h = *(const short8*)(vth + voff);
      pv1h = *(const short8*)(vth + voff + 8);
      pv0l = *(const short8*)(vtl + voff);
      pv1l = *(const short8*)(vtl + voff + 8);
    }

    // S = Q K^T / 8  (split: hi·hi + hi·lo + lo·hi)
    floatx4 sc[4];
#pragma unroll
    for (int nt = 0; nt < 4; nt++) {
      int krow = nt * 16 + fr;
      short8 k0h = *(const short8*)&KsH[krow * AP_ + g * 8];
      short8 k1h = *(const short8*)&KsH[krow * AP_ + 32 + g * 8];
      short8 k0l = *(const short8*)&KsL[krow * AP_ + g * 8];
      short8 k1l = *(const short8*)&KsL[krow * AP_ + 32 + g * 8];
      floatx4 z = (floatx4){0.f, 0.f, 0.f, 0.f};
      z = __builtin_amdgcn_mfma_f32_16x16x32_bf16(qf0h, k0h, z, 0, 0, 0);
      z = __builtin_amdgcn_mfma_f32_16x16x32_bf16(qf1h, k1h, z, 0, 0, 0);
      z = __builtin_amdgcn_mfma_f32_16x16x32_bf16(qf0h, k0l, z, 0, 0, 0);
      z = __builtin_amdgcn_mfma_f32_16x16x32_bf16(qf1h, k1l, z, 0, 0, 0);
      z = __builtin_amdgcn_mfma_f32_16x16x32_bf16(qf0l, k0h, z, 0, 0, 0);
      z = __builtin_amdgcn_mfma_f32_16x16x32_bf16(qf1l, k1h, z, 0, 0, 0);
      sc[nt] = z;
    }
#pragma unroll
    for (int nt = 0; nt < 4; nt++)
#pragma unroll
      for (int r = 0; r < 4; r++) sc[nt][r] *= 0.125f;

    // online softmax (f32)
#pragma unroll
    for (int r = 0; r < 4; r++) {
      float mx = fmaxf(fmaxf(sc[0][r], sc[1][r]), fmaxf(sc[2][r], sc[3][r]));
#pragma unroll
      for (int d = 1; d < 16; d <<= 1) mx = fmaxf(mx, __shfl_xor(mx, d));
      float mn = fmaxf(mi_[r], mx);
      alpha[r] = __expf(mi_[r] - mn);
      float rs = 0.f;
#pragma unroll
      for (int nt = 0; nt < 4; nt++) {
        float p = __expf(sc[nt][r] - mn);
        sc[nt][r] = p; rs += p;
      }
#pragma unroll
      for (int d = 1; d < 16; d <<= 1) rs += __shfl_xor(rs, d);
      li_[r] = li_[r] * alpha[r] + rs;
      mi_[r] = mn;
    }
#pragma unroll
    for (int nt = 0; nt < 4; nt++)
#pragma unroll
      for (int r = 0; r < 4; r++) o[nt][r] *= alpha[r];

    __syncthreads();   // B3: ALL waves done reading Ks -> safe to overwrite w/ P

    // P split: C-layout -> K region (per-wave slice) -> A-layout
#pragma unroll
    for (int nt = 0; nt < 4; nt++)
#pragma unroll
      for (int r = 0; r < 4; r++) {
        float p = sc[nt][r];
        bf16 hh2 = f2b(p);
        PwH[((g << 2) + r) * AP_ + nt * 16 + fr] = hh2;
        PwL[((g << 2) + r) * AP_ + nt * 16 + fr] = f2b(p - b2f(hh2));
      }
    // P slices are wave-private: wave-local LDS drain suffices
    asm volatile("s_waitcnt lgkmcnt(0)" ::: "memory");

    short8 p0h = *(const short8*)&PwH[fr * AP_ + g * 8];
    short8 p1h = *(const short8*)&PwH[fr * AP_ + 32 + g * 8];
    short8 p0l = *(const short8*)&PwL[fr * AP_ + g * 8];
    short8 p1l = *(const short8*)&PwL[fr * AP_ + 32 + g * 8];
#pragma unroll
    for (int nt = 0; nt < 4; nt++) {
      int dh = nt * 16 + fr;
      short8 v0h = *(const short8*)&VsH[dh * AP_ + g * 8];
      short8 v1h = *(const short8*)&VsH[dh * AP_ + 32 + g * 8];
      short8 v0l = *(const short8*)&VsL[dh * AP_ + g * 8];
      short8 v1l = *(const short8*)&VsL[dh * AP_ + 32 + g * 8];
      floatx4 z = o[nt];
      z = __builtin_amdgcn_mfma_f32_16x16x32_bf16(p0h, v0h, z, 0, 0, 0);
      z = __builtin_amdgcn_mfma_f32_16x16x32_bf16(p1h, v1h, z, 0, 0, 0);
      z = __builtin_amdgcn_mfma_f32_16x16x32_bf16(p0h, v0l, z, 0, 0, 0);
      z = __builtin_amdgcn_mfma_f32_16x16x32_bf16(p1h, v1l, z, 0, 0, 0);
      z = __builtin_amdgcn_mfma_f32_16x16x32_bf16(p0l, v0h, z, 0, 0, 0);
      z = __builtin_amdgcn_mfma_f32_16x16x32_bf16(p1l, v1h, z, 0, 0, 0);
      o[nt] = z;
    }
  }

#pragma unroll
  for (int nt = 0; nt < 4; nt++) {
#pragma unroll
    for (int r = 0; r < 4; r++) {
      int qrow = q0 + w * 16 + (g << 2) + r;
      float li = fmaxf(li_[r], 1e-20f);
      float v = o[nt][r] / li;
      size_t off = (size_t)(qrow * B_ + b) * D_ + hh * DH_ + nt * 16 + fr;
      bf16 hh2 = f2b(v);
      ch[off] = hh2;
      cl[off] = f2b(v - b2f(hh2));
    }
  }
}

// Batched transpose + cast: src f32 [z][R][C] -> dst bf16 [z][C][R]
__global__ __launch_bounds__(256) void transpose_kernel(
    const float* __restrict__ src, bf16* __restrict__ dst, int R, int C) {
  __shared__ bf16 tile[64][65];
  const int tid = threadIdx.x;
  const size_t boff = (size_t)blockIdx.z * R * C;
  const int c0 = blockIdx.x * 64, r0 = blockIdx.y * 64;
#pragma unroll
  for (int i = 0; i < 2; i++) {
    int rr = i * 32 + tid / 8, cc = (tid % 8) * 8;
    const float* sp = &src[boff + (size_t)(r0 + rr) * C + c0 + cc];
    float4 v0 = *(const float4*)sp;
    float4 v1 = *(const float4*)(sp + 4);
    tile[rr][cc + 0] = f2b(v0.x); tile[rr][cc + 1] = f2b(v0.y);
    tile[rr][cc + 2] = f2b(v0.z); tile[rr][cc + 3] = f2b(v0.w);
    tile[rr][cc + 4] = f2b(v1.x); tile[rr][cc + 5] = f2b(v1.y);
    tile[rr][cc + 6] = f2b(v1.z); tile[rr][cc + 7] = f2b(v1.w);
  }
  __syncthreads();
#pragma unroll
  for (int i = 0; i < 2; i++) {
    int cc = i * 32 + tid / 8, rr = (tid % 8) * 8;
    __attribute__((aligned(16))) bf16 tmp[8];
#pragma unroll
    for (int j = 0; j < 8; j++) tmp[j] = tile[rr + j][cc];
    *(short8*)&dst[boff + (size_t)(c0 + cc) * R + r0 + rr] =
        *(const short8*)tmp;
  }
}

// LayerNorm over D=768, f32 in (optional bf16 add), f32 out. In-place OK.
__global__ __launch_bounds__(256) void ln_kernel(
    const float* __restrict__ x, const bf16* __restrict__ add,
    const float* __restrict__ gam, const float* __restrict__ bet,
    float* __restrict__ out) {
  const int row = blockIdx.x, tid = threadIdx.x;
  float v[3], s = 0.f, sq = 0.f;
#pragma unroll
  for (int j = 0; j < 3; j++) {
    int c = tid + j * 256;
    float t = x[(size_t)row * D_ + c];
    if (add) t += b2f(add[(size_t)row * D_ + c]);
    v[j] = t; s += t; sq += t * t;
  }
#pragma unroll
  for (int d = 1; d < 64; d <<= 1) { s += __shfl_xor(s, d); sq += __shfl_xor(sq, d); }
  __shared__ float ss[4], ssq[4];
  const int w = tid >> 6, lane = tid & 63;
  if (lane == 0) { ss[w] = s; ssq[w] = sq; }
  __syncthreads();
  s = ss[0] + ss[1] + ss[2] + ss[3];
  sq = ssq[0] + ssq[1] + ssq[2] + ssq[3];
  float mean = s * (1.f / D_);
  float var = fmaxf(sq * (1.f / D_) - mean * mean, 0.f);
  float rstd = rsqrtf(var + 1e-5f);
#pragma unroll
  for (int j = 0; j < 3; j++) {
    int c = tid + j * 256;
    out[(size_t)row * D_ + c] = (v[j] - mean) * rstd * gam[c] + bet[c];
  }
}

// Router (all f32): logits -> softmax probs, argmax expert, gate.
__global__ __launch_bounds__(256) void router_kernel(
    const float* __restrict__ x, const float* __restrict__ rw,
    const float* __restrict__ rb, float* __restrict__ probs,
    int* __restrict__ eidx, float* __restrict__ gate) {
  const int tid = threadIdx.x, w = tid >> 6, lane = tid & 63;
  const int t = blockIdx.x * 4 + w;
  float acc[E_];
#pragma unroll
  for (int e = 0; e < E_; e++) acc[e] = 0.f;
  for (int j = 0; j < D_ / 64; j++) {
    int c = lane + j * 64;
    float xv = x[(size_t)t * D_ + c];
#pragma unroll
    for (int e = 0; e < E_; e++) acc[e] += xv * rw[e * D_ + c];
  }
#pragma unroll
  for (int e = 0; e < E_; e++)
#pragma unroll
    for (int d = 1; d < 64; d <<= 1) acc[e] += __shfl_xor(acc[e], d);
  if (lane == 0) {
    float lg[E_], p[E_], mx = -1e30f;
#pragma unroll
    for (int e = 0; e < E_; e++) { lg[e] = acc[e] + rb[e]; mx = fmaxf(mx, lg[e]); }
    float sum = 0.f;
#pragma unroll
    for (int e = 0; e < E_; e++) { p[e] = __expf(lg[e] - mx); sum += p[e]; }
    float inv = 1.f / sum;
    int am = 0; float bm = lg[0];
#pragma unroll
    for (int e = 1; e < E_; e++) if (lg[e] > bm) { bm = lg[e]; am = e; }
#pragma unroll
    for (int e = 0; e < E_; e++) probs[t * E_ + e] = p[e] * inv;
    eidx[t] = am;
    gate[t] = p[am] * inv;
  }
}

// Stable per-expert position scan, counts, lb_loss.
__global__ __launch_bounds__(512) void router_pos_kernel(
    const int* __restrict__ eidx, const float* __restrict__ probs,
    const float* __restrict__ gate, int* __restrict__ stok,
    float* __restrict__ sgate, int* __restrict__ counts,
    float* __restrict__ lb_out) {
  const int tid = threadIdx.x, e = tid >> 6, lane = tid & 63;
  int base = 0; float sump = 0.f;
  for (int c = 0; c < T_ / 64; c++) {
    int t = c * 64 + lane;
    int ei = eidx[t];
    sump += probs[t * E_ + e];
    bool m = (ei == e);
    unsigned long long mask = __ballot(m);
    if (m) {
      int p = base + (int)__popcll(mask & ((1ull << lane) - 1ull));
      if (p < CAP_) {
        stok[e * CAP_ + p] = t;
        sgate[e * CAP_ + p] = gate[t];
      }
    }
    base += (int)__popcll(mask);
  }
#pragma unroll
  for (int d = 1; d < 64; d <<= 1) sump += __shfl_xor(sump, d);
  __shared__ float sP[E_];
  __shared__ int sC[E_];
  if (lane == 0) { counts[e] = base; sC[e] = base; sP[e] = sump; }
  __syncthreads();
  if (tid == 0) {
    float lb = 0.f;
    for (int i = 0; i < E_; i++) lb += (float)sC[i] * sP[i];
    lb *= (float)E_ / ((float)T_ * (float)T_);
    lb_out[0] = lb;
  }
}

// Gather kept tokens (f32 xln -> bf16 xe), zeros for empty slots
__global__ __launch_bounds__(256) void gather_kernel(
    const float* __restrict__ x, const int* __restrict__ stok,
    bf16* __restrict__ xe) {
  int idx = blockIdx.x * 256 + threadIdx.x;   // E*CAP*(D/4)
  int slot = idx / (D_ / 4), r = idx % (D_ / 4);
  int t = stok[slot];
  bf16 o0, o1, o2, o3;
  if (t >= 0) {
    float4 v = *(const float4*)(x + (size_t)t * D_ + r * 4);
    o0 = f2b(v.x); o1 = f2b(v.y); o2 = f2b(v.z); o3 = f2b(v.w);
  } else {
    o0 = o1 = o2 = o3 = f2b(0.f);
  }
  bf16* dst = xe + (size_t)slot * D_ + r * 4;
  dst[0] = o0; dst[1] = o1; dst[2] = o2; dst[3] = o3;
}

// ---------------------------------------------------------------------------
extern "C" void kernel_launch(void* const* d_in, const int* in_sizes, int n_in,
                              void* d_out, int out_size, void* d_ws,
                              size_t ws_size, hipStream_t stream) {
  const float* src   = (const float*)d_in[0];
  const float* in_w  = (const float*)d_in[1];
  const float* in_b  = (const float*)d_in[2];
  const float* out_w = (const float*)d_in[3];
  const float* out_b = (const float*)d_in[4];
  const float* n1g   = (const float*)d_in[5];
  const float* n1b   = (const float*)d_in[6];
  const float* rw    = (const float*)d_in[7];
  const float* rb    = (const float*)d_in[8];
  const float* w1    = (const float*)d_in[9];
  const float* b1    = (const float*)d_in[10];
  const float* w2    = (const float*)d_in[11];
  const float* b2p   = (const float*)d_in[12];
  const float* n2g   = (const float*)d_in[13];
  const float* n2b   = (const float*)d_in[14];
  float* out = (float*)d_out;

  // Workspace: 113,475,840 B total, lifetime-aliased (layout as R7).
  char* ws = (char*)d_ws;
  bf16*  qkv_h  = (bf16*)(ws + 0);
  bf16*  qkv_l  = (bf16*)(ws + 18874368);
  bf16*  w1t    = (bf16*)(ws + 0);
  bf16*  w2t    = (bf16*)(ws + 0);
  bf16*  ctx_h  = (bf16*)(ws + 37748736);
  bf16*  ctx_l  = (bf16*)(ws + 44040192);
  bf16*  xe     = (bf16*)(ws + 37748736);
  bf16*  moe    = (bf16*)(ws + 37748736);
  float* xln    = (float*)(ws + 50331648);
  bf16*  vt_h   = (bf16*)(ws + 62914560);
  bf16*  vt_l   = (bf16*)(ws + 69206016);
  bf16*  hbuf   = (bf16*)(ws + 62914560);
  bf16*  src_h  = (bf16*)(ws + 75497472);   // [T,D]
  bf16*  src_l  = (bf16*)(ws + 81788928);
  bf16*  inw_h  = (bf16*)(ws + 88080384);   // [3D,D]
  bf16*  inw_l  = (bf16*)(ws + 91619328);
  bf16*  outw_h = (bf16*)(ws + 95158272);   // [D,D]
  bf16*  outw_l = (bf16*)(ws + 96337920);
  float* probs  = (float*)(ws + 113246208);
  int*   eidx   = (int*)(ws + 113377280);
  float* gate   = (float*)(ws + 113393664);
  int*   counts = (int*)(ws + 113410048);
  int*   stok   = (int*)(ws + 113410304);
  float* sgate  = (float*)(ws + 113443072);

  (void)in_sizes; (void)n_in; (void)out_size; (void)ws_size;

  hipMemsetAsync(stok, 0xFF, E_ * CAP_ * sizeof(int), stream);   // -1

  // K0: pre-split f32 operands into (hi, lo) bf16 pairs
  split_kernel<<<(T_ * D_ / 4) / 256, 256, 0, stream>>>(src, src_h, src_l,
                                                        T_ * D_ / 4);
  split_kernel<<<(3 * D_ * D_ / 4) / 256, 256, 0, stream>>>(
      in_w, inw_h, inw_l, 3 * D_ * D_ / 4);
  split_kernel<<<(D_ * D_ / 4) / 256, 256, 0, stream>>>(out_w, outw_h, outw_l,
                                                        D_ * D_ / 4);

  // K1: qkv = src @ in_proj_w^T + b  (split-precision, pair output)
  gemm_split_pairout<<<dim3(3 * D_ / 128, T_ / 128), 256, 0, stream>>>(
      SrcPair{src_h, src_l}, SrcPair{inw_h, inw_l}, in_b, qkv_h, qkv_l,
      3 * D_, D_);
  // K2: V pre-transpose -> vt
  vtrans2_kernel<<<dim3(S_ / 64, B_ * H_), 256, 0, stream>>>(
      qkv_h, qkv_l, vt_h, vt_l);
  // K3: flash attention (split precision)
  attn_kernel<<<dim3(S_ / 64, B_ * H_), 256, 0, stream>>>(
      qkv_h, qkv_l, vt_h, vt_l, ctx_h, ctx_l);
  // K4: xpre = ctx @ out_proj_w^T + b + src  (f32 out -> xln buffer)
  gemm_split_f32out<<<dim3(D_ / 128, T_ / 128), 256, 0, stream>>>(
      SrcPair{ctx_h, ctx_l}, SrcPair{outw_h, outw_l}, out_b, src, xln, D_, D_);
  // K5: LN1 in-place (f32)
  ln_kernel<<<T_, 256, 0, stream>>>(xln, nullptr, n1g, n1b, xln);
  // K6: router (f32)
  router_kernel<<<T_ / 4, 256, 0, stream>>>(xln, rw, rb, probs, eidx, gate);
  // K8: positions + counts + lb_loss
  router_pos_kernel<<<1, 512, 0, stream>>>(eidx, probs, gate, stok, sgate,
                                           counts, out + (size_t)T_ * D_);
  // K9: gather (f32 -> bf16)
  gather_kernel<<<(E_ * CAP_ * (D_ / 4)) / 256, 256, 0, stream>>>(xln, stok, xe);
  // K10: w1t[e] = cast(w1[e])^T
  transpose_kernel<<<dim3(F_ / 64, D_ / 64, E_), 256, 0, stream>>>(w1, w1t, D_, F_);
  // K11: h = relu(xe @ w1t^T + b1)
  moe1_kernel<<<dim3(F_ / 128, E_ * (CAP_ / 128)), 256, 0, stream>>>(
      xe, w1t, b1, hbuf, counts);
  // moe buffer becomes live now (xe dead): zero it
  hipMemsetAsync(moe, 0, (size_t)T_ * D_ * sizeof(bf16), stream);
  // K12: w2t[e] = cast(w2[e])^T
  transpose_kernel<<<dim3(D_ / 64, F_ / 64, E_), 256, 0, stream>>>(w2, w2t, F_, D_);
  // K13: moe = scatter((h @ w2t^T + b2) * gate)
  moe2_kernel<<<dim3(D_ / 128, E_ * (CAP_ / 128)), 256, 0, stream>>>(
      hbuf, w2t, b2p, stok, sgate, counts, moe);
  // K14: out = LN2(xln + moe) -> f32 d_out
  ln_kernel<<<T_, 256, 0, stream>>>(xln, moe, n2g, n2b, out);
}

// Round 9
// 876.600 us; speedup vs baseline: 1.0057x; 1.0057x over previous
//
#include <hip/hip_runtime.h>
#include <hip/hip_bf16.h>

// ---------------------------------------------------------------------------
// Switch Transformer encoder layer, MI355X/gfx950.
// S=2048 B=2 D=768 H=12 DH=64 F=3072 E=8 T=4096 CAP=1024.
// Interface: f32 in / f32 out. Pre-router chain uses SPLIT-BF16 MFMA
// (x = hi + lo, 3 MFMAs per product => ~2^-18 relative error) so the
// router argmax matches the f32 reference. MoE FFN is plain bf16 MFMA.
// R9: attn keeps P-alias LDS (34.8KB -> 4 blocks/CU) but drops the
//     min-waves launch bound — R8's (256,4) pinned VGPR=64 and spilled
//     (WRITE_SIZE 12.3->14.6MB, MfmaUtil 15->8%). LDS alone caps at 4
//     blocks/CU; VGPR <=128 still allows 4 waves/SIMD (m69 ladder).
// ---------------------------------------------------------------------------

#define S_   2048
#define B_   2
#define D_   768
#define H_   12
#define DH_  64
#define F_   3072
#define E_   8
#define T_   4096
#define CAP_ 1024

#define AP_  68   // attn LDS row stride (elems): 64 + 4 pad

typedef __hip_bfloat16 bf16;
using short8  = __attribute__((ext_vector_type(8))) short;
using floatx4 = __attribute__((ext_vector_type(4))) float;

__device__ __forceinline__ float b2f(bf16 x) { return __bfloat162float(x); }
__device__ __forceinline__ bf16  f2b(float x) { return __float2bfloat16(x); }

// async global->LDS, 16B/lane; LDS dest = wave-uniform base + lane*16B
__device__ __forceinline__ void gld_lds16(const bf16* g, bf16* l) {
  __builtin_amdgcn_global_load_lds(
      (const __attribute__((address_space(1))) void*)g,
      (__attribute__((address_space(3))) void*)l, 16, 0, 0);
}

struct SrcPair { const bf16* h; const bf16* l; };  // pre-split hi/lo

// f32 -> (hi, lo) bf16 split, 4 elems/thread
__global__ __launch_bounds__(256) void split_kernel(
    const float* __restrict__ x, bf16* __restrict__ h, bf16* __restrict__ l,
    int n4) {
  int i = blockIdx.x * 256 + threadIdx.x;
  if (i >= n4) return;
  float4 v = ((const float4*)x)[i];
  float va[4] = {v.x, v.y, v.z, v.w};
  __attribute__((aligned(8))) bf16 hh[4], ll[4];
#pragma unroll
  for (int j = 0; j < 4; j++) {
    bf16 t = f2b(va[j]);
    hh[j] = t;
    ll[j] = f2b(va[j] - b2f(t));
  }
  *(uint2*)(h + (size_t)i * 4) = *(const uint2*)hh;
  *(uint2*)(l + (size_t)i * 4) = *(const uint2*)ll;
}

// ---------------------------------------------------------------------------
// SPLIT GEMM mainloop: C128x128 += A[128,K]*W[128,K]^T in ~f32 precision.
// m97 staging: global_load_lds width=16, 2 barriers, [128][32] LDS tiles.
// ---------------------------------------------------------------------------
__device__ __forceinline__ void gemm_split_loop(
    SrcPair A, SrcPair W, int K,
    bf16* AsH, bf16* AsL, bf16* WsH, bf16* WsL, floatx4 (&acc)[4][4]) {
  const int tid = threadIdx.x;
  const int w = tid >> 6, lane = tid & 63;
  const int srow = lane >> 2;
  const int scol = (lane & 3) * 8;
  const bf16* Ah = A.h + (size_t)(w * 32 + srow) * K + scol;
  const bf16* Al = A.l + (size_t)(w * 32 + srow) * K + scol;
  const bf16* Wh = W.h + (size_t)(w * 32 + srow) * K + scol;
  const bf16* Wl = W.l + (size_t)(w * 32 + srow) * K + scol;
  bf16* AsHb = AsH + w * 1024;   // wave-uniform LDS bases
  bf16* AsLb = AsL + w * 1024;
  bf16* WsHb = WsH + w * 1024;
  bf16* WsLb = WsL + w * 1024;
  const int wm = (w >> 1) * 64, wn = (w & 1) * 64;
  const int fr = lane & 15, g = lane >> 4;

  for (int kt = 0; kt < K; kt += 32) {
    gld_lds16(Ah, AsHb); gld_lds16(Ah + 16 * (size_t)K, AsHb + 512);
    gld_lds16(Al, AsLb); gld_lds16(Al + 16 * (size_t)K, AsLb + 512);
    gld_lds16(Wh, WsHb); gld_lds16(Wh + 16 * (size_t)K, WsHb + 512);
    gld_lds16(Wl, WsLb); gld_lds16(Wl + 16 * (size_t)K, WsLb + 512);
    Ah += 32; Al += 32; Wh += 32; Wl += 32;
    __syncthreads();
    short8 afh[4], afl[4], bfh[4], bfl[4];
#pragma unroll
    for (int mi = 0; mi < 4; mi++) {
      int o = (wm + mi * 16 + fr) * 32 + g * 8;
      afh[mi] = *(const short8*)&AsH[o];
      afl[mi] = *(const short8*)&AsL[o];
    }
#pragma unroll
    for (int ni = 0; ni < 4; ni++) {
      int o = (wn + ni * 16 + fr) * 32 + g * 8;
      bfh[ni] = *(const short8*)&WsH[o];
      bfl[ni] = *(const short8*)&WsL[o];
    }
#pragma unroll
    for (int mi = 0; mi < 4; mi++)
#pragma unroll
      for (int ni = 0; ni < 4; ni++) {
        floatx4 z = acc[mi][ni];
        z = __builtin_amdgcn_mfma_f32_16x16x32_bf16(afh[mi], bfh[ni], z, 0, 0, 0);
        z = __builtin_amdgcn_mfma_f32_16x16x32_bf16(afh[mi], bfl[ni], z, 0, 0, 0);
        z = __builtin_amdgcn_mfma_f32_16x16x32_bf16(afl[mi], bfh[ni], z, 0, 0, 0);
        acc[mi][ni] = z;
      }
    __syncthreads();
  }
}

// Split GEMM, split-pair output: C = A·W^T + bias -> (Chi, Clo)
__global__ __launch_bounds__(256) void gemm_split_pairout(
    SrcPair A, SrcPair W, const float* __restrict__ bias,
    bf16* __restrict__ Chi, bf16* __restrict__ Clo, int N, int K) {
  __shared__ __attribute__((aligned(16))) bf16 AsH[4096], AsL[4096];
  __shared__ __attribute__((aligned(16))) bf16 WsH[4096], WsL[4096];
  const int m0 = blockIdx.y * 128, n0 = blockIdx.x * 128;
  floatx4 acc[4][4];
#pragma unroll
  for (int i = 0; i < 4; i++)
#pragma unroll
    for (int j = 0; j < 4; j++) acc[i][j] = (floatx4){0.f, 0.f, 0.f, 0.f};
  SrcPair Aoff{A.h + (size_t)m0 * K, A.l + (size_t)m0 * K};
  SrcPair Woff{W.h + (size_t)n0 * K, W.l + (size_t)n0 * K};
  gemm_split_loop(Aoff, Woff, K, AsH, AsL, WsH, WsL, acc);

  const int tid = threadIdx.x, w = tid >> 6, lane = tid & 63;
  const int wm = (w >> 1) * 64, wn = (w & 1) * 64;
  const int fr = lane & 15, rg = (lane >> 4) * 4;
#pragma unroll
  for (int mi = 0; mi < 4; mi++) {
#pragma unroll
    for (int ni = 0; ni < 4; ni++) {
      int n = n0 + wn + ni * 16 + fr;
      float bv = bias[n];
#pragma unroll
      for (int r = 0; r < 4; r++) {
        int m = m0 + wm + mi * 16 + rg + r;
        float v = acc[mi][ni][r] + bv;
        bf16 hh = f2b(v);
        Chi[(size_t)m * N + n] = hh;
        Clo[(size_t)m * N + n] = f2b(v - b2f(hh));
      }
    }
  }
}

// Split GEMM, f32 output + f32 residual: C = A·W^T + bias + resid
__global__ __launch_bounds__(256) void gemm_split_f32out(
    SrcPair A, SrcPair W, const float* __restrict__ bias,
    const float* __restrict__ resid, float* __restrict__ C, int N, int K) {
  __shared__ __attribute__((aligned(16))) bf16 AsH[4096], AsL[4096];
  __shared__ __attribute__((aligned(16))) bf16 WsH[4096], WsL[4096];
  const int m0 = blockIdx.y * 128, n0 = blockIdx.x * 128;
  floatx4 acc[4][4];
#pragma unroll
  for (int i = 0; i < 4; i++)
#pragma unroll
    for (int j = 0; j < 4; j++) acc[i][j] = (floatx4){0.f, 0.f, 0.f, 0.f};
  SrcPair Aoff{A.h + (size_t)m0 * K, A.l + (size_t)m0 * K};
  SrcPair Woff{W.h + (size_t)n0 * K, W.l + (size_t)n0 * K};
  gemm_split_loop(Aoff, Woff, K, AsH, AsL, WsH, WsL, acc);

  const int tid = threadIdx.x, w = tid >> 6, lane = tid & 63;
  const int wm = (w >> 1) * 64, wn = (w & 1) * 64;
  const int fr = lane & 15, rg = (lane >> 4) * 4;
#pragma unroll
  for (int mi = 0; mi < 4; mi++) {
#pragma unroll
    for (int ni = 0; ni < 4; ni++) {
      int n = n0 + wn + ni * 16 + fr;
      float bv = bias[n];
#pragma unroll
      for (int r = 0; r < 4; r++) {
        int m = m0 + wm + mi * 16 + rg + r;
        C[(size_t)m * N + n] = acc[mi][ni][r] + bv + resid[(size_t)m * N + n];
      }
    }
  }
}

// ---------------------------------------------------------------------------
// Plain bf16 GEMM mainloop (MoE path), m97 global_load_lds staging.
// ---------------------------------------------------------------------------
__device__ __forceinline__ void gemm_tile_loop(
    const bf16* __restrict__ Ablk, const bf16* __restrict__ Wblk, int K,
    bf16* As, bf16* Ws, floatx4 (&acc)[4][4]) {
  const int tid = threadIdx.x;
  const int w = tid >> 6, lane = tid & 63;
  const int srow = lane >> 2;
  const int scol = (lane & 3) * 8;
  const bf16* Ag = Ablk + (size_t)(w * 32 + srow) * K + scol;
  const bf16* Wg = Wblk + (size_t)(w * 32 + srow) * K + scol;
  bf16* Asb = As + w * 1024;
  bf16* Wsb = Ws + w * 1024;
  const int wm = (w >> 1) * 64, wn = (w & 1) * 64;
  const int fr = lane & 15, g = lane >> 4;

  for (int kt = 0; kt < K; kt += 32) {
    gld_lds16(Ag, Asb); gld_lds16(Ag + 16 * (size_t)K, Asb + 512);
    gld_lds16(Wg, Wsb); gld_lds16(Wg + 16 * (size_t)K, Wsb + 512);
    Ag += 32; Wg += 32;
    __syncthreads();
    short8 af[4], bfg[4];
#pragma unroll
    for (int mi = 0; mi < 4; mi++)
      af[mi] = *(const short8*)&As[(wm + mi * 16 + fr) * 32 + g * 8];
#pragma unroll
    for (int ni = 0; ni < 4; ni++)
      bfg[ni] = *(const short8*)&Ws[(wn + ni * 16 + fr) * 32 + g * 8];
#pragma unroll
    for (int mi = 0; mi < 4; mi++)
#pragma unroll
      for (int ni = 0; ni < 4; ni++)
        acc[mi][ni] = __builtin_amdgcn_mfma_f32_16x16x32_bf16(
            af[mi], bfg[ni], acc[mi][ni], 0, 0, 0);
    __syncthreads();
  }
}

// MoE FFN layer 1: h = relu(xe @ w1t^T + b1)
__global__ __launch_bounds__(256) void moe1_kernel(
    const bf16* __restrict__ xe, const bf16* __restrict__ w1t,
    const float* __restrict__ b1, bf16* __restrict__ h,
    const int* __restrict__ counts) {
  const int e = blockIdx.y >> 3, lt = blockIdx.y & 7;
  int kept = counts[e]; if (kept > CAP_) kept = CAP_;
  if (lt * 128 >= kept) return;
  __shared__ __attribute__((aligned(16))) bf16 As[4096];
  __shared__ __attribute__((aligned(16))) bf16 Ws[4096];
  const int n0 = blockIdx.x * 128;
  floatx4 acc[4][4];
#pragma unroll
  for (int i = 0; i < 4; i++)
#pragma unroll
    for (int j = 0; j < 4; j++) acc[i][j] = (floatx4){0.f, 0.f, 0.f, 0.f};
  gemm_tile_loop(xe + (size_t)(e * CAP_ + lt * 128) * D_,
                 w1t + (size_t)e * F_ * D_ + (size_t)n0 * D_, D_, As, Ws, acc);

  const int tid = threadIdx.x, w = tid >> 6, lane = tid & 63;
  const int wm = (w >> 1) * 64, wn = (w & 1) * 64;
  const int fr = lane & 15, rg = (lane >> 4) * 4;
#pragma unroll
  for (int mi = 0; mi < 4; mi++) {
#pragma unroll
    for (int ni = 0; ni < 4; ni++) {
      int n = n0 + wn + ni * 16 + fr;
      float bv = b1[e * F_ + n];
#pragma unroll
      for (int r = 0; r < 4; r++) {
        int mrow = lt * 128 + wm + mi * 16 + rg + r;
        h[(size_t)(e * CAP_ + mrow) * F_ + n] =
            f2b(fmaxf(acc[mi][ni][r] + bv, 0.f));
      }
    }
  }
}

// MoE FFN layer 2 + gate + scatter
__global__ __launch_bounds__(256) void moe2_kernel(
    const bf16* __restrict__ h, const bf16* __restrict__ w2t,
    const float* __restrict__ bias2, const int* __restrict__ stok,
    const float* __restrict__ sgate, const int* __restrict__ counts,
    bf16* __restrict__ moe) {
  const int e = blockIdx.y >> 3, lt = blockIdx.y & 7;
  int kept = counts[e]; if (kept > CAP_) kept = CAP_;
  if (lt * 128 >= kept) return;
  __shared__ __attribute__((aligned(16))) bf16 As[4096];
  __shared__ __attribute__((aligned(16))) bf16 Ws[4096];
  const int n0 = blockIdx.x * 128;
  floatx4 acc[4][4];
#pragma unroll
  for (int i = 0; i < 4; i++)
#pragma unroll
    for (int j = 0; j < 4; j++) acc[i][j] = (floatx4){0.f, 0.f, 0.f, 0.f};
  gemm_tile_loop(h + (size_t)(e * CAP_ + lt * 128) * F_,
                 w2t + (size_t)e * D_ * F_ + (size_t)n0 * F_, F_, As, Ws, acc);

  const int tid = threadIdx.x, w = tid >> 6, lane = tid & 63;
  const int wm = (w >> 1) * 64, wn = (w & 1) * 64;
  const int fr = lane & 15, rg = (lane >> 4) * 4;
#pragma unroll
  for (int mi = 0; mi < 4; mi++) {
#pragma unroll
    for (int r = 0; r < 4; r++) {
      int mrow = lt * 128 + wm + mi * 16 + rg + r;
      int slot = e * CAP_ + mrow;
      int t = stok[slot];
      if (t < 0) continue;
      float gt = sgate[slot];
#pragma unroll
      for (int ni = 0; ni < 4; ni++) {
        int n = n0 + wn + ni * 16 + fr;
        moe[(size_t)t * D_ + n] = f2b((acc[mi][ni][r] + bias2[e * D_ + n]) * gt);
      }
    }
  }
}

// ---------------------------------------------------------------------------
// V pre-transpose: qkv V-slice (hi+lo) -> vt[bh][dh][S] (hi+lo).
// ---------------------------------------------------------------------------
__global__ __launch_bounds__(256) void vtrans2_kernel(
    const bf16* __restrict__ qh, const bf16* __restrict__ ql,
    bf16* __restrict__ vth, bf16* __restrict__ vtl) {
  __shared__ bf16 th[64][65], tl[64][65];
  const int tid = threadIdx.x;
  const int bh = blockIdx.y, b = bh / H_, hh = bh % H_;
  const int s0 = blockIdx.x * 64;
#pragma unroll
  for (int i = 0; i < 2; i++) {
    int rr = i * 32 + tid / 8, cc = (tid % 8) * 8;
    size_t off = (size_t)((s0 + rr) * B_ + b) * (3 * D_) + 2 * D_ + hh * DH_ + cc;
    short8 vh = *(const short8*)(qh + off);
    short8 vl = *(const short8*)(ql + off);
    const bf16* ph = (const bf16*)&vh;
    const bf16* pl = (const bf16*)&vl;
#pragma unroll
    for (int j = 0; j < 8; j++) { th[rr][cc + j] = ph[j]; tl[rr][cc + j] = pl[j]; }
  }
  __syncthreads();
#pragma unroll
  for (int i = 0; i < 2; i++) {
    int cc = i * 32 + tid / 8, rr = (tid % 8) * 8;
    __attribute__((aligned(16))) bf16 a[8], c[8];
#pragma unroll
    for (int j = 0; j < 8; j++) { a[j] = th[rr + j][cc]; c[j] = tl[rr + j][cc]; }
    size_t off = ((size_t)bh * DH_ + cc) * S_ + s0 + rr;
    *(short8*)(vth + off) = *(const short8*)a;
    *(short8*)(vtl + off) = *(const short8*)c;
  }
}

// ---------------------------------------------------------------------------
// Flash attention, split-bf16, register prefetch. P-tiles alias the K LDS
// region (K fully consumed by end of QK; post-QK barrier guards overwrite).
// LDS = 2*64*AP (K/P union) + 2*64*AP (V) = 34,816 B -> 4 blocks/CU.
// NO min-waves launch bound: compiler free to use ~88-104 VGPR (<=128 keeps
// 4 waves/SIMD; a (256,4) bound pinned 64 VGPR and spilled -- R8 regression).
// ---------------------------------------------------------------------------
__global__ __launch_bounds__(256) void attn_kernel(
    const bf16* __restrict__ qh, const bf16* __restrict__ ql,
    const bf16* __restrict__ vth, const bf16* __restrict__ vtl,
    bf16* __restrict__ ch, bf16* __restrict__ cl) {
  __shared__ __attribute__((aligned(16))) bf16 KP[2 * 64 * AP_];  // K hi/lo, aliased by P hi/lo
  __shared__ __attribute__((aligned(16))) bf16 VsH[64 * AP_], VsL[64 * AP_];
  const int tid = threadIdx.x, w = tid >> 6, lane = tid & 63;
  const int bh = blockIdx.y, b = bh / H_, hh = bh % H_;
  const int q0 = blockIdx.x * 64;
  const int fr = lane & 15, g = lane >> 4;
  bf16* KsH = KP;
  bf16* KsL = KP + 64 * AP_;
  bf16* PwH = KP + w * (16 * AP_);              // wave-private P slices
  bf16* PwL = KP + 64 * AP_ + w * (16 * AP_);

  const int qs = q0 + w * 16 + fr;
  const size_t qoff = (size_t)(qs * B_ + b) * (3 * D_) + hh * DH_;
  const short8 qf0h = *(const short8*)(qh + qoff + g * 8);
  const short8 qf1h = *(const short8*)(qh + qoff + 32 + g * 8);
  const short8 qf0l = *(const short8*)(ql + qoff + g * 8);
  const short8 qf1l = *(const short8*)(ql + qoff + 32 + g * 8);

  float mi_[4], li_[4], alpha[4];
  floatx4 o[4];
#pragma unroll
  for (int r = 0; r < 4; r++) { mi_[r] = -1e30f; li_[r] = 0.f; }
#pragma unroll
  for (int nt = 0; nt < 4; nt++) o[nt] = (floatx4){0.f, 0.f, 0.f, 0.f};

  const int str = tid >> 2;            // staged row 0..63 (key for K, dh for V)
  const int st16 = (tid & 3) * 16;     // 16-elem chunk

  // prefetch tile 0 into registers
  size_t koff = (size_t)(str * B_ + b) * (3 * D_) + D_ + hh * DH_ + st16;
  size_t voff = ((size_t)bh * DH_ + str) * S_ + st16;
  short8 pk0h = *(const short8*)(qh + koff);
  short8 pk1h = *(const short8*)(qh + koff + 8);
  short8 pk0l = *(const short8*)(ql + koff);
  short8 pk1l = *(const short8*)(ql + koff + 8);
  short8 pv0h = *(const short8*)(vth + voff);
  short8 pv1h = *(const short8*)(vth + voff + 8);
  short8 pv0l = *(const short8*)(vtl + voff);
  short8 pv1l = *(const short8*)(vtl + voff + 8);

  for (int kb = 0; kb < S_ / 64; kb++) {
    __syncthreads();   // B1: prior PV done (P + V reads) -> restage K/V
    *(short8*)&KsH[str * AP_ + st16]     = pk0h;
    *(short8*)&KsH[str * AP_ + st16 + 8] = pk1h;
    *(short8*)&KsL[str * AP_ + st16]     = pk0l;
    *(short8*)&KsL[str * AP_ + st16 + 8] = pk1l;
    *(short8*)&VsH[str * AP_ + st16]     = pv0h;
    *(short8*)&VsH[str * AP_ + st16 + 8] = pv1h;
    *(short8*)&VsL[str * AP_ + st16]     = pv0l;
    *(short8*)&VsL[str * AP_ + st16 + 8] = pv1l;
    __syncthreads();   // B2: staged tile visible

    if (kb + 1 < S_ / 64) {   // prefetch next tile; overlaps compute below
      koff += (size_t)64 * B_ * (3 * D_);
      voff += 64;
      pk0h = *(const short8*)(qh + koff);
      pk1h = *(const short8*)(qh + koff + 8);
      pk0l = *(const short8*)(ql + koff);
      pk1l = *(const short8*)(ql + koff + 8);
      pv0h = *(const short8*)(vth + voff);
      pv1h = *(const short8*)(vth + voff + 8);
      pv0l = *(const short8*)(vtl + voff);
      pv1l = *(const short8*)(vtl + voff + 8);
    }

    // S = Q K^T / 8  (split: hi·hi + hi·lo + lo·hi)
    floatx4 sc[4];
#pragma unroll
    for (int nt = 0; nt < 4; nt++) {
      int krow = nt * 16 + fr;
      short8 k0h = *(const short8*)&KsH[krow * AP_ + g * 8];
      short8 k1h = *(const short8*)&KsH[krow * AP_ + 32 + g * 8];
      short8 k0l = *(const short8*)&KsL[krow * AP_ + g * 8];
      short8 k1l = *(const short8*)&KsL[krow * AP_ + 32 + g * 8];
      floatx4 z = (floatx4){0.f, 0.f, 0.f, 0.f};
      z = __builtin_amdgcn_mfma_f32_16x16x32_bf16(qf0h, k0h, z, 0, 0, 0);
      z = __builtin_amdgcn_mfma_f32_16x16x32_bf16(qf1h, k1h, z, 0, 0, 0);
      z = __builtin_amdgcn_mfma_f32_16x16x32_bf16(qf0h, k0l, z, 0, 0, 0);
      z = __builtin_amdgcn_mfma_f32_16x16x32_bf16(qf1h, k1l, z, 0, 0, 0);
      z = __builtin_amdgcn_mfma_f32_16x16x32_bf16(qf0l, k0h, z, 0, 0, 0);
      z = __builtin_amdgcn_mfma_f32_16x16x32_bf16(qf1l, k1h, z, 0, 0, 0);
      sc[nt] = z;
    }
#pragma unroll
    for (int nt = 0; nt < 4; nt++)
#pragma unroll
      for (int r = 0; r < 4; r++) sc[nt][r] *= 0.125f;

    // online softmax (f32)
#pragma unroll
    for (int r = 0; r < 4; r++) {
      float mx = fmaxf(fmaxf(sc[0][r], sc[1][r]), fmaxf(sc[2][r], sc[3][r]));
#pragma unroll
      for (int d = 1; d < 16; d <<= 1) mx = fmaxf(mx, __shfl_xor(mx, d));
      float mn = fmaxf(mi_[r], mx);
      alpha[r] = __expf(mi_[r] - mn);
      float rs = 0.f;
#pragma unroll
      for (int nt = 0; nt < 4; nt++) {
        float p = __expf(sc[nt][r] - mn);
        sc[nt][r] = p; rs += p;
      }
#pragma unroll
      for (int d = 1; d < 16; d <<= 1) rs += __shfl_xor(rs, d);
      li_[r] = li_[r] * alpha[r] + rs;
      mi_[r] = mn;
    }
#pragma unroll
    for (int nt = 0; nt < 4; nt++)
#pragma unroll
      for (int r = 0; r < 4; r++) o[nt][r] *= alpha[r];

    __syncthreads();   // B3: ALL waves done reading Ks -> safe to overwrite w/ P

    // P split: C-layout -> K region (per-wave slice) -> A-layout
#pragma unroll
    for (int nt = 0; nt < 4; nt++)
#pragma unroll
      for (int r = 0; r < 4; r++) {
        float p = sc[nt][r];
        bf16 hh2 = f2b(p);
        PwH[((g << 2) + r) * AP_ + nt * 16 + fr] = hh2;
        PwL[((g << 2) + r) * AP_ + nt * 16 + fr] = f2b(p - b2f(hh2));
      }
    // P slices are wave-private: wave-local LDS drain suffices
    asm volatile("s_waitcnt lgkmcnt(0)" ::: "memory");

    short8 p0h = *(const short8*)&PwH[fr * AP_ + g * 8];
    short8 p1h = *(const short8*)&PwH[fr * AP_ + 32 + g * 8];
    short8 p0l = *(const short8*)&PwL[fr * AP_ + g * 8];
    short8 p1l = *(const short8*)&PwL[fr * AP_ + 32 + g * 8];
#pragma unroll
    for (int nt = 0; nt < 4; nt++) {
      int dh = nt * 16 + fr;
      short8 v0h = *(const short8*)&VsH[dh * AP_ + g * 8];
      short8 v1h = *(const short8*)&VsH[dh * AP_ + 32 + g * 8];
      short8 v0l = *(const short8*)&VsL[dh * AP_ + g * 8];
      short8 v1l = *(const short8*)&VsL[dh * AP_ + 32 + g * 8];
      floatx4 z = o[nt];
      z = __builtin_amdgcn_mfma_f32_16x16x32_bf16(p0h, v0h, z, 0, 0, 0);
      z = __builtin_amdgcn_mfma_f32_16x16x32_bf16(p1h, v1h, z, 0, 0, 0);
      z = __builtin_amdgcn_mfma_f32_16x16x32_bf16(p0h, v0l, z, 0, 0, 0);
      z = __builtin_amdgcn_mfma_f32_16x16x32_bf16(p1h, v1l, z, 0, 0, 0);
      z = __builtin_amdgcn_mfma_f32_16x16x32_bf16(p0l, v0h, z, 0, 0, 0);
      z = __builtin_amdgcn_mfma_f32_16x16x32_bf16(p1l, v1h, z, 0, 0, 0);
      o[nt] = z;
    }
  }

#pragma unroll
  for (int nt = 0; nt < 4; nt++) {
#pragma unroll
    for (int r = 0; r < 4; r++) {
      int qrow = q0 + w * 16 + (g << 2) + r;
      float li = fmaxf(li_[r], 1e-20f);
      float v = o[nt][r] / li;
      size_t off = (size_t)(qrow * B_ + b) * D_ + hh * DH_ + nt * 16 + fr;
      bf16 hh2 = f2b(v);
      ch[off] = hh2;
      cl[off] = f2b(v - b2f(hh2));
    }
  }
}

// Batched transpose + cast: src f32 [z][R][C] -> dst bf16 [z][C][R]
__global__ __launch_bounds__(256) void transpose_kernel(
    const float* __restrict__ src, bf16* __restrict__ dst, int R, int C) {
  __shared__ bf16 tile[64][65];
  const int tid = threadIdx.x;
  const size_t boff = (size_t)blockIdx.z * R * C;
  const int c0 = blockIdx.x * 64, r0 = blockIdx.y * 64;
#pragma unroll
  for (int i = 0; i < 2; i++) {
    int rr = i * 32 + tid / 8, cc = (tid % 8) * 8;
    const float* sp = &src[boff + (size_t)(r0 + rr) * C + c0 + cc];
    float4 v0 = *(const float4*)sp;
    float4 v1 = *(const float4*)(sp + 4);
    tile[rr][cc + 0] = f2b(v0.x); tile[rr][cc + 1] = f2b(v0.y);
    tile[rr][cc + 2] = f2b(v0.z); tile[rr][cc + 3] = f2b(v0.w);
    tile[rr][cc + 4] = f2b(v1.x); tile[rr][cc + 5] = f2b(v1.y);
    tile[rr][cc + 6] = f2b(v1.z); tile[rr][cc + 7] = f2b(v1.w);
  }
  __syncthreads();
#pragma unroll
  for (int i = 0; i < 2; i++) {
    int cc = i * 32 + tid / 8, rr = (tid % 8) * 8;
    __attribute__((aligned(16))) bf16 tmp[8];
#pragma unroll
    for (int j = 0; j < 8; j++) tmp[j] = tile[rr + j][cc];
    *(short8*)&dst[boff + (size_t)(c0 + cc) * R + r0 + rr] =
        *(const short8*)tmp;
  }
}

// LayerNorm over D=768, f32 in (optional bf16 add), f32 out. In-place OK.
__global__ __launch_bounds__(256) void ln_kernel(
    const float* __restrict__ x, const bf16* __restrict__ add,
    const float* __restrict__ gam, const float* __restrict__ bet,
    float* __restrict__ out) {
  const int row = blockIdx.x, tid = threadIdx.x;
  float v[3], s = 0.f, sq = 0.f;
#pragma unroll
  for (int j = 0; j < 3; j++) {
    int c = tid + j * 256;
    float t = x[(size_t)row * D_ + c];
    if (add) t += b2f(add[(size_t)row * D_ + c]);
    v[j] = t; s += t; sq += t * t;
  }
#pragma unroll
  for (int d = 1; d < 64; d <<= 1) { s += __shfl_xor(s, d); sq += __shfl_xor(sq, d); }
  __shared__ float ss[4], ssq[4];
  const int w = tid >> 6, lane = tid & 63;
  if (lane == 0) { ss[w] = s; ssq[w] = sq; }
  __syncthreads();
  s = ss[0] + ss[1] + ss[2] + ss[3];
  sq = ssq[0] + ssq[1] + ssq[2] + ssq[3];
  float mean = s * (1.f / D_);
  float var = fmaxf(sq * (1.f / D_) - mean * mean, 0.f);
  float rstd = rsqrtf(var + 1e-5f);
#pragma unroll
  for (int j = 0; j < 3; j++) {
    int c = tid + j * 256;
    out[(size_t)row * D_ + c] = (v[j] - mean) * rstd * gam[c] + bet[c];
  }
}

// Router (all f32): logits -> softmax probs, argmax expert, gate.
__global__ __launch_bounds__(256) void router_kernel(
    const float* __restrict__ x, const float* __restrict__ rw,
    const float* __restrict__ rb, float* __restrict__ probs,
    int* __restrict__ eidx, float* __restrict__ gate) {
  const int tid = threadIdx.x, w = tid >> 6, lane = tid & 63;
  const int t = blockIdx.x * 4 + w;
  float acc[E_];
#pragma unroll
  for (int e = 0; e < E_; e++) acc[e] = 0.f;
  for (int j = 0; j < D_ / 64; j++) {
    int c = lane + j * 64;
    float xv = x[(size_t)t * D_ + c];
#pragma unroll
    for (int e = 0; e < E_; e++) acc[e] += xv * rw[e * D_ + c];
  }
#pragma unroll
  for (int e = 0; e < E_; e++)
#pragma unroll
    for (int d = 1; d < 64; d <<= 1) acc[e] += __shfl_xor(acc[e], d);
  if (lane == 0) {
    float lg[E_], p[E_], mx = -1e30f;
#pragma unroll
    for (int e = 0; e < E_; e++) { lg[e] = acc[e] + rb[e]; mx = fmaxf(mx, lg[e]); }
    float sum = 0.f;
#pragma unroll
    for (int e = 0; e < E_; e++) { p[e] = __expf(lg[e] - mx); sum += p[e]; }
    float inv = 1.f / sum;
    int am = 0; float bm = lg[0];
#pragma unroll
    for (int e = 1; e < E_; e++) if (lg[e] > bm) { bm = lg[e]; am = e; }
#pragma unroll
    for (int e = 0; e < E_; e++) probs[t * E_ + e] = p[e] * inv;
    eidx[t] = am;
    gate[t] = p[am] * inv;
  }
}

// Stable per-expert position scan, counts, lb_loss.
__global__ __launch_bounds__(512) void router_pos_kernel(
    const int* __restrict__ eidx, const float* __restrict__ probs,
    const float* __restrict__ gate, int* __restrict__ stok,
    float* __restrict__ sgate, int* __restrict__ counts,
    float* __restrict__ lb_out) {
  const int tid = threadIdx.x, e = tid >> 6, lane = tid & 63;
  int base = 0; float sump = 0.f;
  for (int c = 0; c < T_ / 64; c++) {
    int t = c * 64 + lane;
    int ei = eidx[t];
    sump += probs[t * E_ + e];
    bool m = (ei == e);
    unsigned long long mask = __ballot(m);
    if (m) {
      int p = base + (int)__popcll(mask & ((1ull << lane) - 1ull));
      if (p < CAP_) {
        stok[e * CAP_ + p] = t;
        sgate[e * CAP_ + p] = gate[t];
      }
    }
    base += (int)__popcll(mask);
  }
#pragma unroll
  for (int d = 1; d < 64; d <<= 1) sump += __shfl_xor(sump, d);
  __shared__ float sP[E_];
  __shared__ int sC[E_];
  if (lane == 0) { counts[e] = base; sC[e] = base; sP[e] = sump; }
  __syncthreads();
  if (tid == 0) {
    float lb = 0.f;
    for (int i = 0; i < E_; i++) lb += (float)sC[i] * sP[i];
    lb *= (float)E_ / ((float)T_ * (float)T_);
    lb_out[0] = lb;
  }
}

// Gather kept tokens (f32 xln -> bf16 xe), zeros for empty slots
__global__ __launch_bounds__(256) void gather_kernel(
    const float* __restrict__ x, const int* __restrict__ stok,
    bf16* __restrict__ xe) {
  int idx = blockIdx.x * 256 + threadIdx.x;   // E*CAP*(D/4)
  int slot = idx / (D_ / 4), r = idx % (D_ / 4);
  int t = stok[slot];
  bf16 o0, o1, o2, o3;
  if (t >= 0) {
    float4 v = *(const float4*)(x + (size_t)t * D_ + r * 4);
    o0 = f2b(v.x); o1 = f2b(v.y); o2 = f2b(v.z); o3 = f2b(v.w);
  } else {
    o0 = o1 = o2 = o3 = f2b(0.f);
  }
  bf16* dst = xe + (size_t)slot * D_ + r * 4;
  dst[0] = o0; dst[1] = o1; dst[2] = o2; dst[3] = o3;
}

// ---------------------------------------------------------------------------
extern "C" void kernel_launch(void* const* d_in, const int* in_sizes, int n_in,
                              void* d_out, int out_size, void* d_ws,
                              size_t ws_size, hipStream_t stream) {
  const float* src   = (const float*)d_in[0];
  const float* in_w  = (const float*)d_in[1];
  const float* in_b  = (const float*)d_in[2];
  const float* out_w = (const float*)d_in[3];
  const float* out_b = (const float*)d_in[4];
  const float* n1g   = (const float*)d_in[5];
  const float* n1b   = (const float*)d_in[6];
  const float* rw    = (const float*)d_in[7];
  const float* rb    = (const float*)d_in[8];
  const float* w1    = (const float*)d_in[9];
  const float* b1    = (const float*)d_in[10];
  const float* w2    = (const float*)d_in[11];
  const float* b2p   = (const float*)d_in[12];
  const float* n2g   = (const float*)d_in[13];
  const float* n2b   = (const float*)d_in[14];
  float* out = (float*)d_out;

  // Workspace: 113,475,840 B total, lifetime-aliased (layout as R7).
  char* ws = (char*)d_ws;
  bf16*  qkv_h  = (bf16*)(ws + 0);
  bf16*  qkv_l  = (bf16*)(ws + 18874368);
  bf16*  w1t    = (bf16*)(ws + 0);
  bf16*  w2t    = (bf16*)(ws + 0);
  bf16*  ctx_h  = (bf16*)(ws + 37748736);
  bf16*  ctx_l  = (bf16*)(ws + 44040192);
  bf16*  xe     = (bf16*)(ws + 37748736);
  bf16*  moe    = (bf16*)(ws + 37748736);
  float* xln    = (float*)(ws + 50331648);
  bf16*  vt_h   = (bf16*)(ws + 62914560);
  bf16*  vt_l   = (bf16*)(ws + 69206016);
  bf16*  hbuf   = (bf16*)(ws + 62914560);
  bf16*  src_h  = (bf16*)(ws + 75497472);   // [T,D]
  bf16*  src_l  = (bf16*)(ws + 81788928);
  bf16*  inw_h  = (bf16*)(ws + 88080384);   // [3D,D]
  bf16*  inw_l  = (bf16*)(ws + 91619328);
  bf16*  outw_h = (bf16*)(ws + 95158272);   // [D,D]
  bf16*  outw_l = (bf16*)(ws + 96337920);
  float* probs  = (float*)(ws + 113246208);
  int*   eidx   = (int*)(ws + 113377280);
  float* gate   = (float*)(ws + 113393664);
  int*   counts = (int*)(ws + 113410048);
  int*   stok   = (int*)(ws + 113410304);
  float* sgate  = (float*)(ws + 113443072);

  (void)in_sizes; (void)n_in; (void)out_size; (void)ws_size;

  hipMemsetAsync(stok, 0xFF, E_ * CAP_ * sizeof(int), stream);   // -1

  // K0: pre-split f32 operands into (hi, lo) bf16 pairs
  split_kernel<<<(T_ * D_ / 4) / 256, 256, 0, stream>>>(src, src_h, src_l,
                                                        T_ * D_ / 4);
  split_kernel<<<(3 * D_ * D_ / 4) / 256, 256, 0, stream>>>(
      in_w, inw_h, inw_l, 3 * D_ * D_ / 4);
  split_kernel<<<(D_ * D_ / 4) / 256, 256, 0, stream>>>(out_w, outw_h, outw_l,
                                                        D_ * D_ / 4);

  // K1: qkv = src @ in_proj_w^T + b  (split-precision, pair output)
  gemm_split_pairout<<<dim3(3 * D_ / 128, T_ / 128), 256, 0, stream>>>(
      SrcPair{src_h, src_l}, SrcPair{inw_h, inw_l}, in_b, qkv_h, qkv_l,
      3 * D_, D_);
  // K2: V pre-transpose -> vt
  vtrans2_kernel<<<dim3(S_ / 64, B_ * H_), 256, 0, stream>>>(
      qkv_h, qkv_l, vt_h, vt_l);
  // K3: flash attention (split precision)
  attn_kernel<<<dim3(S_ / 64, B_ * H_), 256, 0, stream>>>(
      qkv_h, qkv_l, vt_h, vt_l, ctx_h, ctx_l);
  // K4: xpre = ctx @ out_proj_w^T + b + src  (f32 out -> xln buffer)
  gemm_split_f32out<<<dim3(D_ / 128, T_ / 128), 256, 0, stream>>>(
      SrcPair{ctx_h, ctx_l}, SrcPair{outw_h, outw_l}, out_b, src, xln, D_, D_);
  // K5: LN1 in-place (f32)
  ln_kernel<<<T_, 256, 0, stream>>>(xln, nullptr, n1g, n1b, xln);
  // K6: router (f32)
  router_kernel<<<T_ / 4, 256, 0, stream>>>(xln, rw, rb, probs, eidx, gate);
  // K8: positions + counts + lb_loss
  router_pos_kernel<<<1, 512, 0, stream>>>(eidx, probs, gate, stok, sgate,
                                           counts, out + (size_t)T_ * D_);
  // K9: gather (f32 -> bf16)
  gather_kernel<<<(E_ * CAP_ * (D_ / 4)) / 256, 256, 0, stream>>>(xln, stok, xe);
  // K10: w1t[e] = cast(w1[e])^T
  transpose_kernel<<<dim3(F_ / 64, D_ / 64, E_), 256, 0, stream>>>(w1, w1t, D_, F_);
  // K11: h = relu(xe @ w1t^T + b1)
  moe1_kernel<<<dim3(F_ / 128, E_ * (CAP_ / 128)), 256, 0, stream>>>(
      xe, w1t, b1, hbuf, counts);
  // moe buffer becomes live now (xe dead): zero it
  hipMemsetAsync(moe, 0, (size_t)T_ * D_ * sizeof(bf16), stream);
  // K12: w2t[e] = cast(w2[e])^T
  transpose_kernel<<<dim3(D_ / 64, F_ / 64, E_), 256, 0, stream>>>(w2, w2t, F_, D_);
  // K13: moe = scatter((h @ w2t^T + b2) * gate)
  moe2_kernel<<<dim3(D_ / 128, E_ * (CAP_ / 128)), 256, 0, stream>>>(
      hbuf, w2t, b2p, stok, sgate, counts, moe);
  // K14: out = LN2(xln + moe) -> f32 d_out
  ln_kernel<<<T_, 256, 0, stream>>>(xln, moe, n2g, n2b, out);
}

// Round 10
// 663.590 us; speedup vs baseline: 1.3285x; 1.3210x over previous
//
#include <hip/hip_runtime.h>
#include <hip/hip_bf16.h>

// ---------------------------------------------------------------------------
// Switch Transformer encoder layer, MI355X/gfx950.
// S=2048 B=2 D=768 H=12 DH=64 F=3072 E=8 T=4096 CAP=1024.
// Interface: f32 in / f32 out. Pre-router chain uses SPLIT-BF16 MFMA
// (x = hi + lo, 3 MFMAs per product => ~2^-18 relative error) so the
// router argmax matches the f32 reference. MoE FFN is plain bf16 MFMA.
// R10: revert to R7 structure everywhere (best measured: 703us).
//   - R8/R9's P<->K LDS aliasing + 3rd barrier halved MfmaUtil (8.6%) even
//     after the spill fix -> aliasing defeats lgkmcnt batching. Reverted.
//   - R8's m97 gld_lds GEMM staging was ~-19us vs R7 explicit prefetch at
//     these shapes (K=768/3072; m102 curve says ~320TF regime). Reverted.
//   One change vs R7: attention P roundtrip packs (hi,lo) into one u32
//   LDS array -> 32 ds_write_b16 become 16 ds_write_b32 (LDS pipe is the
//   saturated resource: ~80 LDS instr + 32 shfl per wave-iter).
// ---------------------------------------------------------------------------

#define S_   2048
#define B_   2
#define D_   768
#define H_   12
#define DH_  64
#define F_   3072
#define E_   8
#define T_   4096
#define CAP_ 1024

#define AP_  68   // attn LDS row stride (elems): 64 + 4 pad

typedef __hip_bfloat16 bf16;
using short8  = __attribute__((ext_vector_type(8))) short;
using floatx4 = __attribute__((ext_vector_type(4))) float;

__device__ __forceinline__ float b2f(bf16 x) { return __bfloat162float(x); }
__device__ __forceinline__ bf16  f2b(float x) { return __float2bfloat16(x); }

struct SrcPair { const bf16* h; const bf16* l; };  // pre-split hi/lo

// f32 -> (hi, lo) bf16 split, 4 elems/thread
__global__ __launch_bounds__(256) void split_kernel(
    const float* __restrict__ x, bf16* __restrict__ h, bf16* __restrict__ l,
    int n4) {
  int i = blockIdx.x * 256 + threadIdx.x;
  if (i >= n4) return;
  float4 v = ((const float4*)x)[i];
  float va[4] = {v.x, v.y, v.z, v.w};
  __attribute__((aligned(8))) bf16 hh[4], ll[4];
#pragma unroll
  for (int j = 0; j < 4; j++) {
    bf16 t = f2b(va[j]);
    hh[j] = t;
    ll[j] = f2b(va[j] - b2f(t));
  }
  *(uint2*)(h + (size_t)i * 4) = *(const uint2*)hh;
  *(uint2*)(l + (size_t)i * 4) = *(const uint2*)ll;
}

// ---------------------------------------------------------------------------
// SPLIT GEMM mainloop: C128x128 += A[128,K]*W[128,K]^T in ~f32 precision.
// Pre-split operands; register prefetch of next k-tile (R7-proven).
// ---------------------------------------------------------------------------
__device__ __forceinline__ void gemm_split_loop(
    SrcPair A, SrcPair W, int K,
    bf16* AsH, bf16* AsL, bf16* WsH, bf16* WsL, floatx4 (&acc)[4][4]) {
  const int tid = threadIdx.x;
  const int w = tid >> 6, lane = tid & 63;
  const int srow = lane >> 2;
  const int scol = (lane & 3) * 8;
  const int r0 = w * 32 + srow;
  const int lds0 = (w * 32 + srow) * 32 + scol;
  const int wm = (w >> 1) * 64, wn = (w & 1) * 64;
  const int fr = lane & 15, g = lane >> 4;

  size_t o0 = (size_t)r0 * K + scol;
  size_t o1 = (size_t)(r0 + 16) * K + scol;
  short8 ah0 = *(const short8*)(A.h + o0), al0 = *(const short8*)(A.l + o0);
  short8 ah1 = *(const short8*)(A.h + o1), al1 = *(const short8*)(A.l + o1);
  short8 wh0 = *(const short8*)(W.h + o0), wl0 = *(const short8*)(W.l + o0);
  short8 wh1 = *(const short8*)(W.h + o1), wl1 = *(const short8*)(W.l + o1);

  for (int kt = 0; kt < K; kt += 32) {
    o0 += 32; o1 += 32;
    __syncthreads();
    *(short8*)(AsH + lds0)       = ah0;
    *(short8*)(AsH + lds0 + 512) = ah1;
    *(short8*)(AsL + lds0)       = al0;
    *(short8*)(AsL + lds0 + 512) = al1;
    *(short8*)(WsH + lds0)       = wh0;
    *(short8*)(WsH + lds0 + 512) = wh1;
    *(short8*)(WsL + lds0)       = wl0;
    *(short8*)(WsL + lds0 + 512) = wl1;
    __syncthreads();
    if (kt + 32 < K) {   // prefetch next tile; latency overlaps MFMA below
      ah0 = *(const short8*)(A.h + o0); al0 = *(const short8*)(A.l + o0);
      ah1 = *(const short8*)(A.h + o1); al1 = *(const short8*)(A.l + o1);
      wh0 = *(const short8*)(W.h + o0); wl0 = *(const short8*)(W.l + o0);
      wh1 = *(const short8*)(W.h + o1); wl1 = *(const short8*)(W.l + o1);
    }
    short8 afh[4], afl[4], bfh[4], bfl[4];
#pragma unroll
    for (int mi = 0; mi < 4; mi++) {
      int o = (wm + mi * 16 + fr) * 32 + g * 8;
      afh[mi] = *(const short8*)&AsH[o];
      afl[mi] = *(const short8*)&AsL[o];
    }
#pragma unroll
    for (int ni = 0; ni < 4; ni++) {
      int o = (wn + ni * 16 + fr) * 32 + g * 8;
      bfh[ni] = *(const short8*)&WsH[o];
      bfl[ni] = *(const short8*)&WsL[o];
    }
#pragma unroll
    for (int mi = 0; mi < 4; mi++)
#pragma unroll
      for (int ni = 0; ni < 4; ni++) {
        floatx4 z = acc[mi][ni];
        z = __builtin_amdgcn_mfma_f32_16x16x32_bf16(afh[mi], bfh[ni], z, 0, 0, 0);
        z = __builtin_amdgcn_mfma_f32_16x16x32_bf16(afh[mi], bfl[ni], z, 0, 0, 0);
        z = __builtin_amdgcn_mfma_f32_16x16x32_bf16(afl[mi], bfh[ni], z, 0, 0, 0);
        acc[mi][ni] = z;
      }
  }
}

// Split GEMM, split-pair output: C = A·W^T + bias -> (Chi, Clo)
__global__ __launch_bounds__(256) void gemm_split_pairout(
    SrcPair A, SrcPair W, const float* __restrict__ bias,
    bf16* __restrict__ Chi, bf16* __restrict__ Clo, int N, int K) {
  __shared__ __attribute__((aligned(16))) bf16 AsH[4096], AsL[4096];
  __shared__ __attribute__((aligned(16))) bf16 WsH[4096], WsL[4096];
  const int m0 = blockIdx.y * 128, n0 = blockIdx.x * 128;
  floatx4 acc[4][4];
#pragma unroll
  for (int i = 0; i < 4; i++)
#pragma unroll
    for (int j = 0; j < 4; j++) acc[i][j] = (floatx4){0.f, 0.f, 0.f, 0.f};
  SrcPair Aoff{A.h + (size_t)m0 * K, A.l + (size_t)m0 * K};
  SrcPair Woff{W.h + (size_t)n0 * K, W.l + (size_t)n0 * K};
  gemm_split_loop(Aoff, Woff, K, AsH, AsL, WsH, WsL, acc);

  const int tid = threadIdx.x, w = tid >> 6, lane = tid & 63;
  const int wm = (w >> 1) * 64, wn = (w & 1) * 64;
  const int fr = lane & 15, rg = (lane >> 4) * 4;
#pragma unroll
  for (int mi = 0; mi < 4; mi++) {
#pragma unroll
    for (int ni = 0; ni < 4; ni++) {
      int n = n0 + wn + ni * 16 + fr;
      float bv = bias[n];
#pragma unroll
      for (int r = 0; r < 4; r++) {
        int m = m0 + wm + mi * 16 + rg + r;
        float v = acc[mi][ni][r] + bv;
        bf16 hh = f2b(v);
        Chi[(size_t)m * N + n] = hh;
        Clo[(size_t)m * N + n] = f2b(v - b2f(hh));
      }
    }
  }
}

// Split GEMM, f32 output + f32 residual: C = A·W^T + bias + resid
__global__ __launch_bounds__(256) void gemm_split_f32out(
    SrcPair A, SrcPair W, const float* __restrict__ bias,
    const float* __restrict__ resid, float* __restrict__ C, int N, int K) {
  __shared__ __attribute__((aligned(16))) bf16 AsH[4096], AsL[4096];
  __shared__ __attribute__((aligned(16))) bf16 WsH[4096], WsL[4096];
  const int m0 = blockIdx.y * 128, n0 = blockIdx.x * 128;
  floatx4 acc[4][4];
#pragma unroll
  for (int i = 0; i < 4; i++)
#pragma unroll
    for (int j = 0; j < 4; j++) acc[i][j] = (floatx4){0.f, 0.f, 0.f, 0.f};
  SrcPair Aoff{A.h + (size_t)m0 * K, A.l + (size_t)m0 * K};
  SrcPair Woff{W.h + (size_t)n0 * K, W.l + (size_t)n0 * K};
  gemm_split_loop(Aoff, Woff, K, AsH, AsL, WsH, WsL, acc);

  const int tid = threadIdx.x, w = tid >> 6, lane = tid & 63;
  const int wm = (w >> 1) * 64, wn = (w & 1) * 64;
  const int fr = lane & 15, rg = (lane >> 4) * 4;
#pragma unroll
  for (int mi = 0; mi < 4; mi++) {
#pragma unroll
    for (int ni = 0; ni < 4; ni++) {
      int n = n0 + wn + ni * 16 + fr;
      float bv = bias[n];
#pragma unroll
      for (int r = 0; r < 4; r++) {
        int m = m0 + wm + mi * 16 + rg + r;
        C[(size_t)m * N + n] = acc[mi][ni][r] + bv + resid[(size_t)m * N + n];
      }
    }
  }
}

// ---------------------------------------------------------------------------
// Plain bf16 GEMM mainloop (MoE path), register prefetch (R7-proven).
// ---------------------------------------------------------------------------
__device__ __forceinline__ void gemm_tile_loop(
    const bf16* __restrict__ Ablk, const bf16* __restrict__ Wblk, int K,
    bf16* As, bf16* Ws, floatx4 (&acc)[4][4]) {
  const int tid = threadIdx.x;
  const int w = tid >> 6, lane = tid & 63;
  const int srow = lane >> 2;
  const int scol = (lane & 3) * 8;
  const bf16* Ag = Ablk + (size_t)(w * 32 + srow) * K + scol;
  const bf16* Wg = Wblk + (size_t)(w * 32 + srow) * K + scol;
  bf16* AsW = As + (w * 32 + srow) * 32 + scol;
  bf16* WsW = Ws + (w * 32 + srow) * 32 + scol;
  const int wm = (w >> 1) * 64, wn = (w & 1) * 64;
  const int fr = lane & 15, g = lane >> 4;

  short8 a0 = *(const short8*)(Ag);
  short8 a1 = *(const short8*)(Ag + 16 * (size_t)K);
  short8 w0 = *(const short8*)(Wg);
  short8 w1v = *(const short8*)(Wg + 16 * (size_t)K);

  for (int kt = 0; kt < K; kt += 32) {
    Ag += 32; Wg += 32;
    __syncthreads();
    *(short8*)(AsW)           = a0;
    *(short8*)(AsW + 16 * 32) = a1;
    *(short8*)(WsW)           = w0;
    *(short8*)(WsW + 16 * 32) = w1v;
    __syncthreads();
    if (kt + 32 < K) {
      a0 = *(const short8*)(Ag);
      a1 = *(const short8*)(Ag + 16 * (size_t)K);
      w0 = *(const short8*)(Wg);
      w1v = *(const short8*)(Wg + 16 * (size_t)K);
    }
    short8 af[4], bfg[4];
#pragma unroll
    for (int mi = 0; mi < 4; mi++)
      af[mi] = *(const short8*)&As[(wm + mi * 16 + fr) * 32 + g * 8];
#pragma unroll
    for (int ni = 0; ni < 4; ni++)
      bfg[ni] = *(const short8*)&Ws[(wn + ni * 16 + fr) * 32 + g * 8];
#pragma unroll
    for (int mi = 0; mi < 4; mi++)
#pragma unroll
      for (int ni = 0; ni < 4; ni++)
        acc[mi][ni] = __builtin_amdgcn_mfma_f32_16x16x32_bf16(
            af[mi], bfg[ni], acc[mi][ni], 0, 0, 0);
  }
}

// MoE FFN layer 1: h = relu(xe @ w1t^T + b1)
__global__ __launch_bounds__(256) void moe1_kernel(
    const bf16* __restrict__ xe, const bf16* __restrict__ w1t,
    const float* __restrict__ b1, bf16* __restrict__ h,
    const int* __restrict__ counts) {
  const int e = blockIdx.y >> 3, lt = blockIdx.y & 7;
  int kept = counts[e]; if (kept > CAP_) kept = CAP_;
  if (lt * 128 >= kept) return;
  __shared__ __attribute__((aligned(16))) bf16 As[4096];
  __shared__ __attribute__((aligned(16))) bf16 Ws[4096];
  const int n0 = blockIdx.x * 128;
  floatx4 acc[4][4];
#pragma unroll
  for (int i = 0; i < 4; i++)
#pragma unroll
    for (int j = 0; j < 4; j++) acc[i][j] = (floatx4){0.f, 0.f, 0.f, 0.f};
  gemm_tile_loop(xe + (size_t)(e * CAP_ + lt * 128) * D_,
                 w1t + (size_t)e * F_ * D_ + (size_t)n0 * D_, D_, As, Ws, acc);

  const int tid = threadIdx.x, w = tid >> 6, lane = tid & 63;
  const int wm = (w >> 1) * 64, wn = (w & 1) * 64;
  const int fr = lane & 15, rg = (lane >> 4) * 4;
#pragma unroll
  for (int mi = 0; mi < 4; mi++) {
#pragma unroll
    for (int ni = 0; ni < 4; ni++) {
      int n = n0 + wn + ni * 16 + fr;
      float bv = b1[e * F_ + n];
#pragma unroll
      for (int r = 0; r < 4; r++) {
        int mrow = lt * 128 + wm + mi * 16 + rg + r;
        h[(size_t)(e * CAP_ + mrow) * F_ + n] =
            f2b(fmaxf(acc[mi][ni][r] + bv, 0.f));
      }
    }
  }
}

// MoE FFN layer 2 + gate + scatter
__global__ __launch_bounds__(256) void moe2_kernel(
    const bf16* __restrict__ h, const bf16* __restrict__ w2t,
    const float* __restrict__ bias2, const int* __restrict__ stok,
    const float* __restrict__ sgate, const int* __restrict__ counts,
    bf16* __restrict__ moe) {
  const int e = blockIdx.y >> 3, lt = blockIdx.y & 7;
  int kept = counts[e]; if (kept > CAP_) kept = CAP_;
  if (lt * 128 >= kept) return;
  __shared__ __attribute__((aligned(16))) bf16 As[4096];
  __shared__ __attribute__((aligned(16))) bf16 Ws[4096];
  const int n0 = blockIdx.x * 128;
  floatx4 acc[4][4];
#pragma unroll
  for (int i = 0; i < 4; i++)
#pragma unroll
    for (int j = 0; j < 4; j++) acc[i][j] = (floatx4){0.f, 0.f, 0.f, 0.f};
  gemm_tile_loop(h + (size_t)(e * CAP_ + lt * 128) * F_,
                 w2t + (size_t)e * D_ * F_ + (size_t)n0 * F_, F_, As, Ws, acc);

  const int tid = threadIdx.x, w = tid >> 6, lane = tid & 63;
  const int wm = (w >> 1) * 64, wn = (w & 1) * 64;
  const int fr = lane & 15, rg = (lane >> 4) * 4;
#pragma unroll
  for (int mi = 0; mi < 4; mi++) {
#pragma unroll
    for (int r = 0; r < 4; r++) {
      int mrow = lt * 128 + wm + mi * 16 + rg + r;
      int slot = e * CAP_ + mrow;
      int t = stok[slot];
      if (t < 0) continue;
      float gt = sgate[slot];
#pragma unroll
      for (int ni = 0; ni < 4; ni++) {
        int n = n0 + wn + ni * 16 + fr;
        moe[(size_t)t * D_ + n] = f2b((acc[mi][ni][r] + bias2[e * D_ + n]) * gt);
      }
    }
  }
}

// ---------------------------------------------------------------------------
// V pre-transpose: qkv V-slice (hi+lo) -> vt[bh][dh][S] (hi+lo).
// ---------------------------------------------------------------------------
__global__ __launch_bounds__(256) void vtrans2_kernel(
    const bf16* __restrict__ qh, const bf16* __restrict__ ql,
    bf16* __restrict__ vth, bf16* __restrict__ vtl) {
  __shared__ bf16 th[64][65], tl[64][65];
  const int tid = threadIdx.x;
  const int bh = blockIdx.y, b = bh / H_, hh = bh % H_;
  const int s0 = blockIdx.x * 64;
#pragma unroll
  for (int i = 0; i < 2; i++) {
    int rr = i * 32 + tid / 8, cc = (tid % 8) * 8;
    size_t off = (size_t)((s0 + rr) * B_ + b) * (3 * D_) + 2 * D_ + hh * DH_ + cc;
    short8 vh = *(const short8*)(qh + off);
    short8 vl = *(const short8*)(ql + off);
    const bf16* ph = (const bf16*)&vh;
    const bf16* pl = (const bf16*)&vl;
#pragma unroll
    for (int j = 0; j < 8; j++) { th[rr][cc + j] = ph[j]; tl[rr][cc + j] = pl[j]; }
  }
  __syncthreads();
#pragma unroll
  for (int i = 0; i < 2; i++) {
    int cc = i * 32 + tid / 8, rr = (tid % 8) * 8;
    __attribute__((aligned(16))) bf16 a[8], c[8];
#pragma unroll
    for (int j = 0; j < 8; j++) { a[j] = th[rr + j][cc]; c[j] = tl[rr + j][cc]; }
    size_t off = ((size_t)bh * DH_ + cc) * S_ + s0 + rr;
    *(short8*)(vth + off) = *(const short8*)a;
    *(short8*)(vtl + off) = *(const short8*)c;
  }
}

// ---------------------------------------------------------------------------
// Flash attention, split-bf16, register prefetch, wave-local P sync.
// R7 structure (separate LDS arrays, 2 block barriers). P roundtrip packs
// (hi,lo) into ONE u32 array: 16 ds_write_b32 instead of 32 ds_write_b16.
// LDS = 4*64*AP*2 (K/V) + 4*16*AP*4 (P u32) = 52,224 B.
// ---------------------------------------------------------------------------
__global__ __launch_bounds__(256) void attn_kernel(
    const bf16* __restrict__ qh, const bf16* __restrict__ ql,
    const bf16* __restrict__ vth, const bf16* __restrict__ vtl,
    bf16* __restrict__ ch, bf16* __restrict__ cl) {
  __shared__ __attribute__((aligned(16))) bf16 KsH[64 * AP_], KsL[64 * AP_];
  __shared__ __attribute__((aligned(16))) bf16 VsH[64 * AP_], VsL[64 * AP_];
  __shared__ __attribute__((aligned(16))) unsigned int Ps[4][16 * AP_];
  const int tid = threadIdx.x, w = tid >> 6, lane = tid & 63;
  const int bh = blockIdx.y, b = bh / H_, hh = bh % H_;
  const int q0 = blockIdx.x * 64;
  const int fr = lane & 15, g = lane >> 4;

  const int qs = q0 + w * 16 + fr;
  const size_t qoff = (size_t)(qs * B_ + b) * (3 * D_) + hh * DH_;
  const short8 qf0h = *(const short8*)(qh + qoff + g * 8);
  const short8 qf1h = *(const short8*)(qh + qoff + 32 + g * 8);
  const short8 qf0l = *(const short8*)(ql + qoff + g * 8);
  const short8 qf1l = *(const short8*)(ql + qoff + 32 + g * 8);

  float mi_[4], li_[4], alpha[4];
  floatx4 o[4];
#pragma unroll
  for (int r = 0; r < 4; r++) { mi_[r] = -1e30f; li_[r] = 0.f; }
#pragma unroll
  for (int nt = 0; nt < 4; nt++) o[nt] = (floatx4){0.f, 0.f, 0.f, 0.f};

  const int str = tid >> 2;            // staged row 0..63 (key for K, dh for V)
  const int st16 = (tid & 3) * 16;     // 16-elem chunk

  // prefetch tile 0 into registers
  size_t koff = (size_t)(str * B_ + b) * (3 * D_) + D_ + hh * DH_ + st16;
  size_t voff = ((size_t)bh * DH_ + str) * S_ + st16;
  short8 pk0h = *(const short8*)(qh + koff);
  short8 pk1h = *(const short8*)(qh + koff + 8);
  short8 pk0l = *(const short8*)(ql + koff);
  short8 pk1l = *(const short8*)(ql + koff + 8);
  short8 pv0h = *(const short8*)(vth + voff);
  short8 pv1h = *(const short8*)(vth + voff + 8);
  short8 pv0l = *(const short8*)(vtl + voff);
  short8 pv1l = *(const short8*)(vtl + voff + 8);

  for (int kb = 0; kb < S_ / 64; kb++) {
    __syncthreads();   // B1: all waves finished reading LDS from iter kb-1
    *(short8*)&KsH[str * AP_ + st16]     = pk0h;
    *(short8*)&KsH[str * AP_ + st16 + 8] = pk1h;
    *(short8*)&KsL[str * AP_ + st16]     = pk0l;
    *(short8*)&KsL[str * AP_ + st16 + 8] = pk1l;
    *(short8*)&VsH[str * AP_ + st16]     = pv0h;
    *(short8*)&VsH[str * AP_ + st16 + 8] = pv1h;
    *(short8*)&VsL[str * AP_ + st16]     = pv0l;
    *(short8*)&VsL[str * AP_ + st16 + 8] = pv1l;
    __syncthreads();   // B2: staged tile visible

    if (kb + 1 < S_ / 64) {   // prefetch next tile; overlaps all compute below
      koff += (size_t)64 * B_ * (3 * D_);
      voff += 64;
      pk0h = *(const short8*)(qh + koff);
      pk1h = *(const short8*)(qh + koff + 8);
      pk0l = *(const short8*)(ql + koff);
      pk1l = *(const short8*)(ql + koff + 8);
      pv0h = *(const short8*)(vth + voff);
      pv1h = *(const short8*)(vth + voff + 8);
      pv0l = *(const short8*)(vtl + voff);
      pv1l = *(const short8*)(vtl + voff + 8);
    }

    // S = Q K^T / 8  (split: hi·hi + hi·lo + lo·hi)
    floatx4 sc[4];
#pragma unroll
    for (int nt = 0; nt < 4; nt++) {
      int krow = nt * 16 + fr;
      short8 k0h = *(const short8*)&KsH[krow * AP_ + g * 8];
      short8 k1h = *(const short8*)&KsH[krow * AP_ + 32 + g * 8];
      short8 k0l = *(const short8*)&KsL[krow * AP_ + g * 8];
      short8 k1l = *(const short8*)&KsL[krow * AP_ + 32 + g * 8];
      floatx4 z = (floatx4){0.f, 0.f, 0.f, 0.f};
      z = __builtin_amdgcn_mfma_f32_16x16x32_bf16(qf0h, k0h, z, 0, 0, 0);
      z = __builtin_amdgcn_mfma_f32_16x16x32_bf16(qf1h, k1h, z, 0, 0, 0);
      z = __builtin_amdgcn_mfma_f32_16x16x32_bf16(qf0h, k0l, z, 0, 0, 0);
      z = __builtin_amdgcn_mfma_f32_16x16x32_bf16(qf1h, k1l, z, 0, 0, 0);
      z = __builtin_amdgcn_mfma_f32_16x16x32_bf16(qf0l, k0h, z, 0, 0, 0);
      z = __builtin_amdgcn_mfma_f32_16x16x32_bf16(qf1l, k1h, z, 0, 0, 0);
      sc[nt] = z;
    }
#pragma unroll
    for (int nt = 0; nt < 4; nt++)
#pragma unroll
      for (int r = 0; r < 4; r++) sc[nt][r] *= 0.125f;

    // online softmax (f32)
#pragma unroll
    for (int r = 0; r < 4; r++) {
      float mx = fmaxf(fmaxf(sc[0][r], sc[1][r]), fmaxf(sc[2][r], sc[3][r]));
#pragma unroll
      for (int d = 1; d < 16; d <<= 1) mx = fmaxf(mx, __shfl_xor(mx, d));
      float mn = fmaxf(mi_[r], mx);
      alpha[r] = __expf(mi_[r] - mn);
      float rs = 0.f;
#pragma unroll
      for (int nt = 0; nt < 4; nt++) {
        float p = __expf(sc[nt][r] - mn);
        sc[nt][r] = p; rs += p;
      }
#pragma unroll
      for (int d = 1; d < 16; d <<= 1) rs += __shfl_xor(rs, d);
      li_[r] = li_[r] * alpha[r] + rs;
      mi_[r] = mn;
    }
#pragma unroll
    for (int nt = 0; nt < 4; nt++)
#pragma unroll
      for (int r = 0; r < 4; r++) o[nt][r] *= alpha[r];

    // P split: C-layout -> packed u32 LDS (per-wave private) -> A-layout
    unsigned int* Pw = &Ps[w][0];
#pragma unroll
    for (int nt = 0; nt < 4; nt++)
#pragma unroll
      for (int r = 0; r < 4; r++) {
        float p = sc[nt][r];
        bf16 hh2 = f2b(p);
        bf16 ll2 = f2b(p - b2f(hh2));
        unsigned int pk = (unsigned int)(*(unsigned short*)&hh2) |
                          ((unsigned int)(*(unsigned short*)&ll2) << 16);
        Pw[((g << 2) + r) * AP_ + nt * 16 + fr] = pk;
      }
    // Ps is per-wave private: wave-local LDS drain suffices (no block barrier)
    asm volatile("s_waitcnt lgkmcnt(0)" ::: "memory");

    // read back 8-keys-per-chunk packed rows, unpack to hi/lo frags
    uint4 pa0 = *(const uint4*)&Pw[fr * AP_ + g * 8];
    uint4 pa1 = *(const uint4*)&Pw[fr * AP_ + g * 8 + 4];
    uint4 pb0 = *(const uint4*)&Pw[fr * AP_ + 32 + g * 8];
    uint4 pb1 = *(const uint4*)&Pw[fr * AP_ + 32 + g * 8 + 4];
    __attribute__((aligned(16))) unsigned short h0[8], l0[8], h1[8], l1[8];
    {
      unsigned int pk0[8] = {pa0.x, pa0.y, pa0.z, pa0.w, pa1.x, pa1.y, pa1.z, pa1.w};
      unsigned int pk1[8] = {pb0.x, pb0.y, pb0.z, pb0.w, pb1.x, pb1.y, pb1.z, pb1.w};
#pragma unroll
      for (int j = 0; j < 8; j++) {
        h0[j] = (unsigned short)(pk0[j] & 0xffffu);
        l0[j] = (unsigned short)(pk0[j] >> 16);
        h1[j] = (unsigned short)(pk1[j] & 0xffffu);
        l1[j] = (unsigned short)(pk1[j] >> 16);
      }
    }
    short8 p0h = *(const short8*)h0;
    short8 p0l = *(const short8*)l0;
    short8 p1h = *(const short8*)h1;
    short8 p1l = *(const short8*)l1;
#pragma unroll
    for (int nt = 0; nt < 4; nt++) {
      int dh = nt * 16 + fr;
      short8 v0h = *(const short8*)&VsH[dh * AP_ + g * 8];
      short8 v1h = *(const short8*)&VsH[dh * AP_ + 32 + g * 8];
      short8 v0l = *(const short8*)&VsL[dh * AP_ + g * 8];
      short8 v1l = *(const short8*)&VsL[dh * AP_ + 32 + g * 8];
      floatx4 z = o[nt];
      z = __builtin_amdgcn_mfma_f32_16x16x32_bf16(p0h, v0h, z, 0, 0, 0);
      z = __builtin_amdgcn_mfma_f32_16x16x32_bf16(p1h, v1h, z, 0, 0, 0);
      z = __builtin_amdgcn_mfma_f32_16x16x32_bf16(p0h, v0l, z, 0, 0, 0);
      z = __builtin_amdgcn_mfma_f32_16x16x32_bf16(p1h, v1l, z, 0, 0, 0);
      z = __builtin_amdgcn_mfma_f32_16x16x32_bf16(p0l, v0h, z, 0, 0, 0);
      z = __builtin_amdgcn_mfma_f32_16x16x32_bf16(p1l, v1h, z, 0, 0, 0);
      o[nt] = z;
    }
  }

#pragma unroll
  for (int nt = 0; nt < 4; nt++) {
#pragma unroll
    for (int r = 0; r < 4; r++) {
      int qrow = q0 + w * 16 + (g << 2) + r;
      float li = fmaxf(li_[r], 1e-20f);
      float v = o[nt][r] / li;
      size_t off = (size_t)(qrow * B_ + b) * D_ + hh * DH_ + nt * 16 + fr;
      bf16 hh2 = f2b(v);
      ch[off] = hh2;
      cl[off] = f2b(v - b2f(hh2));
    }
  }
}

// Batched transpose + cast: src f32 [z][R][C] -> dst bf16 [z][C][R]
__global__ __launch_bounds__(256) void transpose_kernel(
    const float* __restrict__ src, bf16* __restrict__ dst, int R, int C) {
  __shared__ bf16 tile[64][65];
  const int tid = threadIdx.x;
  const size_t boff = (size_t)blockIdx.z * R * C;
  const int c0 = blockIdx.x * 64, r0 = blockIdx.y * 64;
#pragma unroll
  for (int i = 0; i < 2; i++) {
    int rr = i * 32 + tid / 8, cc = (tid % 8) * 8;
    const float* sp = &src[boff + (size_t)(r0 + rr) * C + c0 + cc];
    float4 v0 = *(const float4*)sp;
    float4 v1 = *(const float4*)(sp + 4);
    tile[rr][cc + 0] = f2b(v0.x); tile[rr][cc + 1] = f2b(v0.y);
    tile[rr][cc + 2] = f2b(v0.z); tile[rr][cc + 3] = f2b(v0.w);
    tile[rr][cc + 4] = f2b(v1.x); tile[rr][cc + 5] = f2b(v1.y);
    tile[rr][cc + 6] = f2b(v1.z); tile[rr][cc + 7] = f2b(v1.w);
  }
  __syncthreads();
#pragma unroll
  for (int i = 0; i < 2; i++) {
    int cc = i * 32 + tid / 8, rr = (tid % 8) * 8;
    __attribute__((aligned(16))) bf16 tmp[8];
#pragma unroll
    for (int j = 0; j < 8; j++) tmp[j] = tile[rr + j][cc];
    *(short8*)&dst[boff + (size_t)(c0 + cc) * R + r0 + rr] =
        *(const short8*)tmp;
  }
}

// LayerNorm over D=768, f32 in (optional bf16 add), f32 out. In-place OK.
__global__ __launch_bounds__(256) void ln_kernel(
    const float* __restrict__ x, const bf16* __restrict__ add,
    const float* __restrict__ gam, const float* __restrict__ bet,
    float* __restrict__ out) {
  const int row = blockIdx.x, tid = threadIdx.x;
  float v[3], s = 0.f, sq = 0.f;
#pragma unroll
  for (int j = 0; j < 3; j++) {
    int c = tid + j * 256;
    float t = x[(size_t)row * D_ + c];
    if (add) t += b2f(add[(size_t)row * D_ + c]);
    v[j] = t; s += t; sq += t * t;
  }
#pragma unroll
  for (int d = 1; d < 64; d <<= 1) { s += __shfl_xor(s, d); sq += __shfl_xor(sq, d); }
  __shared__ float ss[4], ssq[4];
  const int w = tid >> 6, lane = tid & 63;
  if (lane == 0) { ss[w] = s; ssq[w] = sq; }
  __syncthreads();
  s = ss[0] + ss[1] + ss[2] + ss[3];
  sq = ssq[0] + ssq[1] + ssq[2] + ssq[3];
  float mean = s * (1.f / D_);
  float var = fmaxf(sq * (1.f / D_) - mean * mean, 0.f);
  float rstd = rsqrtf(var + 1e-5f);
#pragma unroll
  for (int j = 0; j < 3; j++) {
    int c = tid + j * 256;
    out[(size_t)row * D_ + c] = (v[j] - mean) * rstd * gam[c] + bet[c];
  }
}

// Router (all f32): logits -> softmax probs, argmax expert, gate.
__global__ __launch_bounds__(256) void router_kernel(
    const float* __restrict__ x, const float* __restrict__ rw,
    const float* __restrict__ rb, float* __restrict__ probs,
    int* __restrict__ eidx, float* __restrict__ gate) {
  const int tid = threadIdx.x, w = tid >> 6, lane = tid & 63;
  const int t = blockIdx.x * 4 + w;
  float acc[E_];
#pragma unroll
  for (int e = 0; e < E_; e++) acc[e] = 0.f;
  for (int j = 0; j < D_ / 64; j++) {
    int c = lane + j * 64;
    float xv = x[(size_t)t * D_ + c];
#pragma unroll
    for (int e = 0; e < E_; e++) acc[e] += xv * rw[e * D_ + c];
  }
#pragma unroll
  for (int e = 0; e < E_; e++)
#pragma unroll
    for (int d = 1; d < 64; d <<= 1) acc[e] += __shfl_xor(acc[e], d);
  if (lane == 0) {
    float lg[E_], p[E_], mx = -1e30f;
#pragma unroll
    for (int e = 0; e < E_; e++) { lg[e] = acc[e] + rb[e]; mx = fmaxf(mx, lg[e]); }
    float sum = 0.f;
#pragma unroll
    for (int e = 0; e < E_; e++) { p[e] = __expf(lg[e] - mx); sum += p[e]; }
    float inv = 1.f / sum;
    int am = 0; float bm = lg[0];
#pragma unroll
    for (int e = 1; e < E_; e++) if (lg[e] > bm) { bm = lg[e]; am = e; }
#pragma unroll
    for (int e = 0; e < E_; e++) probs[t * E_ + e] = p[e] * inv;
    eidx[t] = am;
    gate[t] = p[am] * inv;
  }
}

// Stable per-expert position scan, counts, lb_loss.
__global__ __launch_bounds__(512) void router_pos_kernel(
    const int* __restrict__ eidx, const float* __restrict__ probs,
    const float* __restrict__ gate, int* __restrict__ stok,
    float* __restrict__ sgate, int* __restrict__ counts,
    float* __restrict__ lb_out) {
  const int tid = threadIdx.x, e = tid >> 6, lane = tid & 63;
  int base = 0; float sump = 0.f;
  for (int c = 0; c < T_ / 64; c++) {
    int t = c * 64 + lane;
    int ei = eidx[t];
    sump += probs[t * E_ + e];
    bool m = (ei == e);
    unsigned long long mask = __ballot(m);
    if (m) {
      int p = base + (int)__popcll(mask & ((1ull << lane) - 1ull));
      if (p < CAP_) {
        stok[e * CAP_ + p] = t;
        sgate[e * CAP_ + p] = gate[t];
      }
    }
    base += (int)__popcll(mask);
  }
#pragma unroll
  for (int d = 1; d < 64; d <<= 1) sump += __shfl_xor(sump, d);
  __shared__ float sP[E_];
  __shared__ int sC[E_];
  if (lane == 0) { counts[e] = base; sC[e] = base; sP[e] = sump; }
  __syncthreads();
  if (tid == 0) {
    float lb = 0.f;
    for (int i = 0; i < E_; i++) lb += (float)sC[i] * sP[i];
    lb *= (float)E_ / ((float)T_ * (float)T_);
    lb_out[0] = lb;
  }
}

// Gather kept tokens (f32 xln -> bf16 xe), zeros for empty slots
__global__ __launch_bounds__(256) void gather_kernel(
    const float* __restrict__ x, const int* __restrict__ stok,
    bf16* __restrict__ xe) {
  int idx = blockIdx.x * 256 + threadIdx.x;   // E*CAP*(D/4)
  int slot = idx / (D_ / 4), r = idx % (D_ / 4);
  int t = stok[slot];
  bf16 o0, o1, o2, o3;
  if (t >= 0) {
    float4 v = *(const float4*)(x + (size_t)t * D_ + r * 4);
    o0 = f2b(v.x); o1 = f2b(v.y); o2 = f2b(v.z); o3 = f2b(v.w);
  } else {
    o0 = o1 = o2 = o3 = f2b(0.f);
  }
  bf16* dst = xe + (size_t)slot * D_ + r * 4;
  dst[0] = o0; dst[1] = o1; dst[2] = o2; dst[3] = o3;
}

// ---------------------------------------------------------------------------
extern "C" void kernel_launch(void* const* d_in, const int* in_sizes, int n_in,
                              void* d_out, int out_size, void* d_ws,
                              size_t ws_size, hipStream_t stream) {
  const float* src   = (const float*)d_in[0];
  const float* in_w  = (const float*)d_in[1];
  const float* in_b  = (const float*)d_in[2];
  const float* out_w = (const float*)d_in[3];
  const float* out_b = (const float*)d_in[4];
  const float* n1g   = (const float*)d_in[5];
  const float* n1b   = (const float*)d_in[6];
  const float* rw    = (const float*)d_in[7];
  const float* rb    = (const float*)d_in[8];
  const float* w1    = (const float*)d_in[9];
  const float* b1    = (const float*)d_in[10];
  const float* w2    = (const float*)d_in[11];
  const float* b2p   = (const float*)d_in[12];
  const float* n2g   = (const float*)d_in[13];
  const float* n2b   = (const float*)d_in[14];
  float* out = (float*)d_out;

  // Workspace: 113,475,840 B total, lifetime-aliased (layout as R7).
  char* ws = (char*)d_ws;
  bf16*  qkv_h  = (bf16*)(ws + 0);
  bf16*  qkv_l  = (bf16*)(ws + 18874368);
  bf16*  w1t    = (bf16*)(ws + 0);
  bf16*  w2t    = (bf16*)(ws + 0);
  bf16*  ctx_h  = (bf16*)(ws + 37748736);
  bf16*  ctx_l  = (bf16*)(ws + 44040192);
  bf16*  xe     = (bf16*)(ws + 37748736);
  bf16*  moe    = (bf16*)(ws + 37748736);
  float* xln    = (float*)(ws + 50331648);
  bf16*  vt_h   = (bf16*)(ws + 62914560);
  bf16*  vt_l   = (bf16*)(ws + 69206016);
  bf16*  hbuf   = (bf16*)(ws + 62914560);
  bf16*  src_h  = (bf16*)(ws + 75497472);   // [T,D]
  bf16*  src_l  = (bf16*)(ws + 81788928);
  bf16*  inw_h  = (bf16*)(ws + 88080384);   // [3D,D]
  bf16*  inw_l  = (bf16*)(ws + 91619328);
  bf16*  outw_h = (bf16*)(ws + 95158272);   // [D,D]
  bf16*  outw_l = (bf16*)(ws + 96337920);
  float* probs  = (float*)(ws + 113246208);
  int*   eidx   = (int*)(ws + 113377280);
  float* gate   = (float*)(ws + 113393664);
  int*   counts = (int*)(ws + 113410048);
  int*   stok   = (int*)(ws + 113410304);
  float* sgate  = (float*)(ws + 113443072);

  (void)in_sizes; (void)n_in; (void)out_size; (void)ws_size;

  hipMemsetAsync(stok, 0xFF, E_ * CAP_ * sizeof(int), stream);   // -1

  // K0: pre-split f32 operands into (hi, lo) bf16 pairs
  split_kernel<<<(T_ * D_ / 4) / 256, 256, 0, stream>>>(src, src_h, src_l,
                                                        T_ * D_ / 4);
  split_kernel<<<(3 * D_ * D_ / 4) / 256, 256, 0, stream>>>(
      in_w, inw_h, inw_l, 3 * D_ * D_ / 4);
  split_kernel<<<(D_ * D_ / 4) / 256, 256, 0, stream>>>(out_w, outw_h, outw_l,
                                                        D_ * D_ / 4);

  // K1: qkv = src @ in_proj_w^T + b  (split-precision, pair output)
  gemm_split_pairout<<<dim3(3 * D_ / 128, T_ / 128), 256, 0, stream>>>(
      SrcPair{src_h, src_l}, SrcPair{inw_h, inw_l}, in_b, qkv_h, qkv_l,
      3 * D_, D_);
  // K2: V pre-transpose -> vt
  vtrans2_kernel<<<dim3(S_ / 64, B_ * H_), 256, 0, stream>>>(
      qkv_h, qkv_l, vt_h, vt_l);
  // K3: flash attention (split precision)
  attn_kernel<<<dim3(S_ / 64, B_ * H_), 256, 0, stream>>>(
      qkv_h, qkv_l, vt_h, vt_l, ctx_h, ctx_l);
  // K4: xpre = ctx @ out_proj_w^T + b + src  (f32 out -> xln buffer)
  gemm_split_f32out<<<dim3(D_ / 128, T_ / 128), 256, 0, stream>>>(
      SrcPair{ctx_h, ctx_l}, SrcPair{outw_h, outw_l}, out_b, src, xln, D_, D_);
  // K5: LN1 in-place (f32)
  ln_kernel<<<T_, 256, 0, stream>>>(xln, nullptr, n1g, n1b, xln);
  // K6: router (f32)
  router_kernel<<<T_ / 4, 256, 0, stream>>>(xln, rw, rb, probs, eidx, gate);
  // K8: positions + counts + lb_loss
  router_pos_kernel<<<1, 512, 0, stream>>>(eidx, probs, gate, stok, sgate,
                                           counts, out + (size_t)T_ * D_);
  // K9: gather (f32 -> bf16)
  gather_kernel<<<(E_ * CAP_ * (D_ / 4)) / 256, 256, 0, stream>>>(xln, stok, xe);
  // K10: w1t[e] = cast(w1[e])^T
  transpose_kernel<<<dim3(F_ / 64, D_ / 64, E_), 256, 0, stream>>>(w1, w1t, D_, F_);
  // K11: h = relu(xe @ w1t^T + b1)
  moe1_kernel<<<dim3(F_ / 128, E_ * (CAP_ / 128)), 256, 0, stream>>>(
      xe, w1t, b1, hbuf, counts);
  // moe buffer becomes live now (xe dead): zero it
  hipMemsetAsync(moe, 0, (size_t)T_ * D_ * sizeof(bf16), stream);
  // K12: w2t[e] = cast(w2[e])^T
  transpose_kernel<<<dim3(D_ / 64, F_ / 64, E_), 256, 0, stream>>>(w2, w2t, F_, D_);
  // K13: moe = scatter((h @ w2t^T + b2) * gate)
  moe2_kernel<<<dim3(D_ / 128, E_ * (CAP_ / 128)), 256, 0, stream>>>(
      hbuf, w2t, b2p, stok, sgate, counts, moe);
  // K14: out = LN2(xln + moe) -> f32 d_out
  ln_kernel<<<T_, 256, 0, stream>>>(xln, moe, n2g, n2b, out);
}